// Round 1
// baseline (4336.576 us; speedup 1.0000x reference)
//
#include <hip/hip_runtime.h>
#include <math.h>

#define DEV __device__ __forceinline__

// ---------------- direct conv + bias + BN + ReLU (NCHW) ----------------
template<int IC, int K, int S, int P>
__global__ void conv_bn_relu_kernel(
    const float* __restrict__ x, const float* __restrict__ w,
    const float* __restrict__ cb, const float* __restrict__ bg,
    const float* __restrict__ bb, const float* __restrict__ bm,
    const float* __restrict__ bv,
    float* __restrict__ out,
    int N, int OC, int IH, int IW, int OH, int OW)
{
    int tid = blockIdx.x * blockDim.x + threadIdx.x;
    int total = N * OC * OH * OW;
    if (tid >= total) return;
    int ow = tid % OW;
    int tmp = tid / OW;
    int oh = tmp % OH;
    tmp /= OH;
    int oc = tmp % OC;
    int n  = tmp / OC;

    const float* xb = x + (size_t)n * IC * IH * IW;
    const float* wc = w + (size_t)oc * IC * K * K;
    float acc = 0.f;
    for (int ic = 0; ic < IC; ++ic) {
        const float* xi = xb + (size_t)ic * IH * IW;
        const float* wi = wc + ic * K * K;
        #pragma unroll
        for (int kh = 0; kh < K; ++kh) {
            int ih = oh * S - P + kh;
            if (ih < 0 || ih >= IH) continue;
            #pragma unroll
            for (int kw = 0; kw < K; ++kw) {
                int iw = ow * S - P + kw;
                if (iw < 0 || iw >= IW) continue;
                acc = fmaf(xi[ih * IW + iw], wi[kh * K + kw], acc);
            }
        }
    }
    float scale = bg[oc] * rsqrtf(bv[oc] + 1e-5f);
    float val = (acc + cb[oc] - bm[oc]) * scale + bb[oc];
    out[tid] = val > 0.f ? val : 0.f;
}

// ---------------- quantum gate helpers (16-amp statevector in LDS) ----------------
DEV void gate_ry(float* re, float* im, int q, float th) {
    float c = cosf(th * 0.5f), s = sinf(th * 0.5f);
    int mask = 8 >> q;
    for (int i = 0; i < 16; ++i) {
        if (i & mask) continue;
        int j = i | mask;
        float r0 = re[i], i0 = im[i], r1 = re[j], i1 = im[j];
        re[i] = c * r0 - s * r1;  im[i] = c * i0 - s * i1;
        re[j] = s * r0 + c * r1;  im[j] = s * i0 + c * i1;
    }
}
DEV void gate_rx(float* re, float* im, int q, float th) {
    float c = cosf(th * 0.5f), s = sinf(th * 0.5f);
    int mask = 8 >> q;
    for (int i = 0; i < 16; ++i) {
        if (i & mask) continue;
        int j = i | mask;
        float r0 = re[i], i0 = im[i], r1 = re[j], i1 = im[j];
        // new0 = c*s0 - i*s*s1 ; new1 = -i*s*s0 + c*s1
        re[i] = c * r0 + s * i1;  im[i] = c * i0 - s * r1;
        re[j] = s * i0 + c * r1;  im[j] = -s * r0 + c * i1;
    }
}
DEV void gate_rz(float* re, float* im, int q, float th) {
    float c = cosf(th * 0.5f), s = sinf(th * 0.5f);
    int mask = 8 >> q;
    for (int i = 0; i < 16; ++i) {
        float sg = (i & mask) ? s : -s;    // amp *= (c + i*sg)
        float r = re[i], m = im[i];
        re[i] = c * r - sg * m;
        im[i] = c * m + sg * r;
    }
}
DEV void gate_cnot(float* re, float* im, int c, int t) {
    int cm = 8 >> c, tm = 8 >> t;
    for (int i = 0; i < 16; ++i) {
        if ((i & cm) && !(i & tm)) {
            int j = i | tm;
            float r = re[i]; re[i] = re[j]; re[j] = r;
            float m = im[i]; im[i] = im[j]; im[j] = m;
        }
    }
}

// ---------------- fused head: pool -> linear/tanh -> circuit -> MLP ----------------
__global__ __launch_bounds__(256) void head_kernel(
    const float* __restrict__ conv3out,  // (N,128,14,14)
    const float* __restrict__ pre_w,     // (4,512)
    const float* __restrict__ pre_b,     // (4,)
    const float* __restrict__ qw,        // (2,4,3)
    const float* __restrict__ pw1,       // (64,4)
    const float* __restrict__ pb1,       // (64,)
    const float* __restrict__ pw2,       // (5,64)
    const float* __restrict__ pb2,       // (5,)
    float* __restrict__ out)             // (N,5)
{
    __shared__ float f[512];
    __shared__ float ang[4];
    __shared__ float sre[16], simg[16];
    __shared__ float zexp[4];
    __shared__ float h1[64];

    int b = blockIdx.x;
    int t = threadIdx.x;

    // AdaptiveAvgPool2d((2,2)) on (128,14,14): 512 pooled features
    const float* src = conv3out + (size_t)b * 128 * 196;
    for (int p = t; p < 512; p += 256) {
        int c = p >> 2, i = (p >> 1) & 1, j = p & 1;
        const float* sp = src + c * 196 + (i * 7) * 14 + j * 7;
        float s = 0.f;
        #pragma unroll
        for (int u = 0; u < 7; ++u)
            #pragma unroll
            for (int v = 0; v < 7; ++v)
                s += sp[u * 14 + v];
        f[p] = s * (1.f / 49.f);
    }
    __syncthreads();

    // angles: 4 dot products of length 512, one wave each
    int wv = t >> 6, lane = t & 63;
    float partial = 0.f;
    for (int d = lane; d < 512; d += 64)
        partial += f[d] * pre_w[wv * 512 + d];
    #pragma unroll
    for (int off = 32; off > 0; off >>= 1)
        partial += __shfl_down(partial, off, 64);
    if (lane == 0)
        ang[wv] = tanhf(partial + pre_b[wv]) * 3.14159265358979323846f;
    __syncthreads();

    // 4-qubit statevector sim, single thread (tiny)
    if (t == 0) {
        for (int i = 0; i < 16; ++i) { sre[i] = 0.f; simg[i] = 0.f; }
        sre[0] = 1.f;
        for (int q = 0; q < 4; ++q) gate_ry(sre, simg, q, ang[q]);
        for (int l = 0; l < 2; ++l) {
            for (int q = 0; q < 4; ++q) {
                const float* qq = qw + (l * 4 + q) * 3;
                gate_rx(sre, simg, q, qq[0]);
                gate_ry(sre, simg, q, qq[1]);
                gate_rz(sre, simg, q, qq[2]);
            }
            gate_cnot(sre, simg, 0, 1);
            gate_cnot(sre, simg, 1, 2);
            gate_cnot(sre, simg, 2, 3);
            gate_cnot(sre, simg, 3, 0);
        }
        for (int q = 0; q < 4; ++q) {
            float z = 0.f;
            for (int i = 0; i < 16; ++i) {
                float p2 = sre[i] * sre[i] + simg[i] * simg[i];
                z += (((i >> (3 - q)) & 1) ? -p2 : p2);
            }
            zexp[q] = z;
        }
    }
    __syncthreads();

    // h1 = relu(z @ pw1.T + pb1)
    if (t < 64) {
        float s = pb1[t];
        #pragma unroll
        for (int k = 0; k < 4; ++k) s += zexp[k] * pw1[t * 4 + k];
        h1[t] = s > 0.f ? s : 0.f;
    }
    __syncthreads();

    // out = h1 @ pw2.T + pb2
    if (t < 5) {
        float s = pb2[t];
        for (int k = 0; k < 64; ++k) s += h1[k] * pw2[t * 64 + k];
        out[b * 5 + t] = s;
    }
}

extern "C" void kernel_launch(void* const* d_in, const int* in_sizes, int n_in,
                              void* d_out, int out_size, void* d_ws, size_t ws_size,
                              hipStream_t stream) {
    const float* x    = (const float*)d_in[0];
    const float* c1w  = (const float*)d_in[1];
    const float* c1b  = (const float*)d_in[2];
    const float* bn1g = (const float*)d_in[3];
    const float* bn1b = (const float*)d_in[4];
    const float* bn1m = (const float*)d_in[5];
    const float* bn1v = (const float*)d_in[6];
    const float* c2w  = (const float*)d_in[7];
    const float* c2b  = (const float*)d_in[8];
    const float* bn2g = (const float*)d_in[9];
    const float* bn2b = (const float*)d_in[10];
    const float* bn2m = (const float*)d_in[11];
    const float* bn2v = (const float*)d_in[12];
    const float* c3w  = (const float*)d_in[13];
    const float* c3b  = (const float*)d_in[14];
    const float* bn3g = (const float*)d_in[15];
    const float* bn3b = (const float*)d_in[16];
    const float* bn3m = (const float*)d_in[17];
    const float* bn3v = (const float*)d_in[18];
    const float* prw  = (const float*)d_in[19];
    const float* prb  = (const float*)d_in[20];
    const float* qw   = (const float*)d_in[21];
    const float* pw1  = (const float*)d_in[22];
    const float* pb1  = (const float*)d_in[23];
    const float* pw2  = (const float*)d_in[24];
    const float* pb2  = (const float*)d_in[25];

    const int N = in_sizes[0] / (3 * 224 * 224);   // 128

    float* c1o = (float*)d_ws;                        // N*32*56*56
    float* c2o = c1o + (size_t)N * 32 * 56 * 56;      // N*64*28*28
    float* c3o = c2o + (size_t)N * 64 * 28 * 28;      // N*128*14*14

    {
        int total = N * 32 * 56 * 56;
        conv_bn_relu_kernel<3, 7, 4, 3><<<(total + 255) / 256, 256, 0, stream>>>(
            x, c1w, c1b, bn1g, bn1b, bn1m, bn1v, c1o, N, 32, 224, 224, 56, 56);
    }
    {
        int total = N * 64 * 28 * 28;
        conv_bn_relu_kernel<32, 3, 2, 1><<<(total + 255) / 256, 256, 0, stream>>>(
            c1o, c2w, c2b, bn2g, bn2b, bn2m, bn2v, c2o, N, 64, 56, 56, 28, 28);
    }
    {
        int total = N * 128 * 14 * 14;
        conv_bn_relu_kernel<64, 3, 2, 1><<<(total + 255) / 256, 256, 0, stream>>>(
            c2o, c3w, c3b, bn3g, bn3b, bn3m, bn3v, c3o, N, 128, 28, 28, 14, 14);
    }
    head_kernel<<<N, 256, 0, stream>>>(c3o, prw, prb, qw, pw1, pb1, pw2, pb2,
                                       (float*)d_out);
}

// Round 2
// 1796.594 us; speedup vs baseline: 2.4138x; 2.4138x over previous
//
#include <hip/hip_runtime.h>
#include <math.h>

#define DEV __device__ __forceinline__

// ============ prep: transpose weights [OC][KT] -> [KT][OC]; fold BN ============
template<int OC, int KT>
__global__ void prep_kernel(const float* __restrict__ w,
                            const float* __restrict__ cb,
                            const float* __restrict__ bg, const float* __restrict__ bb,
                            const float* __restrict__ bm, const float* __restrict__ bv,
                            float* __restrict__ wt, float* __restrict__ scale,
                            float* __restrict__ shift)
{
    int tid = blockIdx.x * blockDim.x + threadIdx.x;
    if (tid < OC) {
        float sc = bg[tid] * rsqrtf(bv[tid] + 1e-5f);
        scale[tid] = sc;
        shift[tid] = (cb[tid] - bm[tid]) * sc + bb[tid];
    }
    int stride = gridDim.x * blockDim.x;
    for (int e = tid; e < OC * KT; e += stride) {
        int oc = e / KT, k = e % KT;
        wt[k * OC + oc] = w[e];
    }
}

// ============ implicit-GEMM conv + BN + ReLU ============
// M = N*OH*OW (spatial), N-dim = OC, K = IC*KS*KS. 8x8 register tile.
template<int IC, int KS, int S, int P, int IH, int IW, int OH, int OW, int OC,
         int BM, int BN>
__global__ __launch_bounds__(256, 4) void conv_gemm_kernel(
    const float* __restrict__ x,      // (N,IC,IH,IW)
    const float* __restrict__ wt,     // (KT,OC) transposed weights
    const float* __restrict__ scale,  // (OC)
    const float* __restrict__ shift,  // (OC)
    float* __restrict__ out)          // (N,OC,OH,OW)
{
    constexpr int KT = IC * KS * KS;
    constexpr int BK = 8;
    constexpr int KITER = (KT + BK - 1) / BK;
    constexpr int TM = 8, TN = 8;
    constexpr int MT = BM / TM;            // 64 (conv1) or 32
    constexpr int NT = BN / TN;            // 4 (conv1) or 8
    static_assert(MT * NT == 256, "thread count");
    constexpr int ALD = BM / 32;           // A elems per thread per row
    constexpr int BLD = (BK * BN) / 256;   // B elems per thread
    constexpr int OHW = OH * OW;
    static_assert(OHW % 4 == 0, "float4 store");

    __shared__ float As[BK][BM];
    __shared__ float Bs[BK][BN];

    const int tid = threadIdx.x;
    const int bm0 = blockIdx.x * BM;
    const int oc0 = blockIdx.y * BN;

    const int tmi = tid % MT;
    const int tni = tid / MT;

    // A-load assignment: row akk (0..7), ALD consecutive m
    const int akk = tid / 32;
    const int am0 = (tid % 32) * ALD;

    float acc[TM][TN];
    #pragma unroll
    for (int i = 0; i < TM; ++i)
        #pragma unroll
        for (int j = 0; j < TN; ++j) acc[i][j] = 0.f;

    for (int kt = 0; kt < KITER; ++kt) {
        const int k0 = kt * BK;

        // ---- gather A (im2col) into registers ----
        float av[ALD];
        {
            int kg = k0 + akk;
            if (kg < KT) {
                int ic = kg / (KS * KS);
                int r  = kg % (KS * KS);
                int kh = r / KS, kw = r % KS;
                #pragma unroll
                for (int i = 0; i < ALD; ++i) {
                    int m = bm0 + am0 + i;
                    int n = m / OHW;
                    int s = m % OHW;
                    int oh = s / OW, ow = s % OW;
                    int ih = oh * S - P + kh;
                    int iw = ow * S - P + kw;
                    float v = 0.f;
                    if (ih >= 0 && ih < IH && iw >= 0 && iw < IW)
                        v = x[(((size_t)n * IC + ic) * IH + ih) * IW + iw];
                    av[i] = v;
                }
            } else {
                #pragma unroll
                for (int i = 0; i < ALD; ++i) av[i] = 0.f;
            }
        }
        // ---- gather B (transposed weights) ----
        float bvr[BLD];
        #pragma unroll
        for (int i = 0; i < BLD; ++i) {
            int e = tid + i * 256;
            int kk = e / BN, oc = e % BN;
            int kg = k0 + kk;
            bvr[i] = (kg < KT) ? wt[(size_t)kg * OC + oc0 + oc] : 0.f;
        }

        __syncthreads();   // previous compute done before LDS overwrite
        #pragma unroll
        for (int i = 0; i < ALD; ++i) As[akk][am0 + i] = av[i];
        #pragma unroll
        for (int i = 0; i < BLD; ++i) {
            int e = tid + i * 256;
            Bs[e / BN][e % BN] = bvr[i];
        }
        __syncthreads();

        // ---- 8x8 outer-product accumulate ----
        #pragma unroll
        for (int kk = 0; kk < BK; ++kk) {
            float4 alo = *(const float4*)&As[kk][tmi * 4];
            float4 ahi = *(const float4*)&As[kk][tmi * 4 + BM / 2];
            float4 blo = *(const float4*)&Bs[kk][tni * TN];
            float4 bhi = *(const float4*)&Bs[kk][tni * TN + 4];
            float a[TM] = {alo.x, alo.y, alo.z, alo.w, ahi.x, ahi.y, ahi.z, ahi.w};
            float b[TN] = {blo.x, blo.y, blo.z, blo.w, bhi.x, bhi.y, bhi.z, bhi.w};
            #pragma unroll
            for (int i = 0; i < TM; ++i)
                #pragma unroll
                for (int j = 0; j < TN; ++j)
                    acc[i][j] = fmaf(a[i], b[j], acc[i][j]);
        }
    }

    // ---- epilogue: BN + ReLU + coalesced-ish float4 stores ----
    float sc[TN], sh[TN];
    #pragma unroll
    for (int j = 0; j < TN; ++j) {
        int oc = oc0 + tni * TN + j;
        sc[j] = scale[oc];
        sh[j] = shift[oc];
    }
    #pragma unroll
    for (int half = 0; half < 2; ++half) {
        int mbase = bm0 + half * (BM / 2) + tmi * 4;
        int n = mbase / OHW;
        int s = mbase % OHW;       // groups of 4 never cross n (OHW % 4 == 0)
        #pragma unroll
        for (int j = 0; j < TN; ++j) {
            int oc = oc0 + tni * TN + j;
            float4 v;
            v.x = fmaf(acc[half * 4 + 0][j], sc[j], sh[j]);
            v.y = fmaf(acc[half * 4 + 1][j], sc[j], sh[j]);
            v.z = fmaf(acc[half * 4 + 2][j], sc[j], sh[j]);
            v.w = fmaf(acc[half * 4 + 3][j], sc[j], sh[j]);
            v.x = v.x > 0.f ? v.x : 0.f;
            v.y = v.y > 0.f ? v.y : 0.f;
            v.z = v.z > 0.f ? v.z : 0.f;
            v.w = v.w > 0.f ? v.w : 0.f;
            *(float4*)&out[((size_t)n * OC + oc) * OHW + s] = v;
        }
    }
}

// ============ quantum gate helpers ============
DEV void gate_ry(float* re, float* im, int q, float th) {
    float c = cosf(th * 0.5f), s = sinf(th * 0.5f);
    int mask = 8 >> q;
    for (int i = 0; i < 16; ++i) {
        if (i & mask) continue;
        int j = i | mask;
        float r0 = re[i], i0 = im[i], r1 = re[j], i1 = im[j];
        re[i] = c * r0 - s * r1;  im[i] = c * i0 - s * i1;
        re[j] = s * r0 + c * r1;  im[j] = s * i0 + c * i1;
    }
}
DEV void gate_rx(float* re, float* im, int q, float th) {
    float c = cosf(th * 0.5f), s = sinf(th * 0.5f);
    int mask = 8 >> q;
    for (int i = 0; i < 16; ++i) {
        if (i & mask) continue;
        int j = i | mask;
        float r0 = re[i], i0 = im[i], r1 = re[j], i1 = im[j];
        re[i] = c * r0 + s * i1;  im[i] = c * i0 - s * r1;
        re[j] = s * i0 + c * r1;  im[j] = -s * r0 + c * i1;
    }
}
DEV void gate_rz(float* re, float* im, int q, float th) {
    float c = cosf(th * 0.5f), s = sinf(th * 0.5f);
    int mask = 8 >> q;
    for (int i = 0; i < 16; ++i) {
        float sg = (i & mask) ? s : -s;
        float r = re[i], m = im[i];
        re[i] = c * r - sg * m;
        im[i] = c * m + sg * r;
    }
}
DEV void gate_cnot(float* re, float* im, int c, int t) {
    int cm = 8 >> c, tm = 8 >> t;
    for (int i = 0; i < 16; ++i) {
        if ((i & cm) && !(i & tm)) {
            int j = i | tm;
            float r = re[i]; re[i] = re[j]; re[j] = r;
            float m = im[i]; im[i] = im[j]; im[j] = m;
        }
    }
}

// ============ fused head: pool -> linear/tanh -> circuit -> MLP ============
__global__ __launch_bounds__(256) void head_kernel(
    const float* __restrict__ conv3out,  // (N,128,14,14)
    const float* __restrict__ pre_w, const float* __restrict__ pre_b,
    const float* __restrict__ qw,
    const float* __restrict__ pw1, const float* __restrict__ pb1,
    const float* __restrict__ pw2, const float* __restrict__ pb2,
    float* __restrict__ out)             // (N,5)
{
    __shared__ float f[512];
    __shared__ float ang[4];
    __shared__ float sre[16], simg[16];
    __shared__ float zexp[4];
    __shared__ float h1[64];

    int b = blockIdx.x;
    int t = threadIdx.x;

    const float* src = conv3out + (size_t)b * 128 * 196;
    for (int p = t; p < 512; p += 256) {
        int c = p >> 2, i = (p >> 1) & 1, j = p & 1;
        const float* sp = src + c * 196 + (i * 7) * 14 + j * 7;
        float s = 0.f;
        #pragma unroll
        for (int u = 0; u < 7; ++u)
            #pragma unroll
            for (int v = 0; v < 7; ++v)
                s += sp[u * 14 + v];
        f[p] = s * (1.f / 49.f);
    }
    __syncthreads();

    int wv = t >> 6, lane = t & 63;
    float partial = 0.f;
    for (int d = lane; d < 512; d += 64)
        partial += f[d] * pre_w[wv * 512 + d];
    #pragma unroll
    for (int off = 32; off > 0; off >>= 1)
        partial += __shfl_down(partial, off, 64);
    if (lane == 0)
        ang[wv] = tanhf(partial + pre_b[wv]) * 3.14159265358979323846f;
    __syncthreads();

    if (t == 0) {
        for (int i = 0; i < 16; ++i) { sre[i] = 0.f; simg[i] = 0.f; }
        sre[0] = 1.f;
        for (int q = 0; q < 4; ++q) gate_ry(sre, simg, q, ang[q]);
        for (int l = 0; l < 2; ++l) {
            for (int q = 0; q < 4; ++q) {
                const float* qq = qw + (l * 4 + q) * 3;
                gate_rx(sre, simg, q, qq[0]);
                gate_ry(sre, simg, q, qq[1]);
                gate_rz(sre, simg, q, qq[2]);
            }
            gate_cnot(sre, simg, 0, 1);
            gate_cnot(sre, simg, 1, 2);
            gate_cnot(sre, simg, 2, 3);
            gate_cnot(sre, simg, 3, 0);
        }
        for (int q = 0; q < 4; ++q) {
            float z = 0.f;
            for (int i = 0; i < 16; ++i) {
                float p2 = sre[i] * sre[i] + simg[i] * simg[i];
                z += (((i >> (3 - q)) & 1) ? -p2 : p2);
            }
            zexp[q] = z;
        }
    }
    __syncthreads();

    if (t < 64) {
        float s = pb1[t];
        #pragma unroll
        for (int k = 0; k < 4; ++k) s += zexp[k] * pw1[t * 4 + k];
        h1[t] = s > 0.f ? s : 0.f;
    }
    __syncthreads();

    if (t < 5) {
        float s = pb2[t];
        for (int k = 0; k < 64; ++k) s += h1[k] * pw2[t * 64 + k];
        out[b * 5 + t] = s;
    }
}

extern "C" void kernel_launch(void* const* d_in, const int* in_sizes, int n_in,
                              void* d_out, int out_size, void* d_ws, size_t ws_size,
                              hipStream_t stream) {
    const float* x    = (const float*)d_in[0];
    const float* c1w  = (const float*)d_in[1];
    const float* c1b  = (const float*)d_in[2];
    const float* bn1g = (const float*)d_in[3];
    const float* bn1b = (const float*)d_in[4];
    const float* bn1m = (const float*)d_in[5];
    const float* bn1v = (const float*)d_in[6];
    const float* c2w  = (const float*)d_in[7];
    const float* c2b  = (const float*)d_in[8];
    const float* bn2g = (const float*)d_in[9];
    const float* bn2b = (const float*)d_in[10];
    const float* bn2m = (const float*)d_in[11];
    const float* bn2v = (const float*)d_in[12];
    const float* c3w  = (const float*)d_in[13];
    const float* c3b  = (const float*)d_in[14];
    const float* bn3g = (const float*)d_in[15];
    const float* bn3b = (const float*)d_in[16];
    const float* bn3m = (const float*)d_in[17];
    const float* bn3v = (const float*)d_in[18];
    const float* prw  = (const float*)d_in[19];
    const float* prb  = (const float*)d_in[20];
    const float* qw   = (const float*)d_in[21];
    const float* pw1  = (const float*)d_in[22];
    const float* pb1  = (const float*)d_in[23];
    const float* pw2  = (const float*)d_in[24];
    const float* pb2  = (const float*)d_in[25];

    const int N = in_sizes[0] / (3 * 224 * 224);   // 128

    // workspace layout (floats)
    float* c1o = (float*)d_ws;                         // N*32*56*56 = 12,845,056
    float* c2o = c1o + (size_t)N * 32 * 56 * 56;       // N*64*28*28 =  6,422,528
    float* c3o = c2o + (size_t)N * 64 * 28 * 28;       // N*128*14*14 = 3,211,264
    float* wt1 = c3o + (size_t)N * 128 * 14 * 14;      // 147*32
    float* sc1 = wt1 + 147 * 32;  float* sh1 = sc1 + 32;
    float* wt2 = sh1 + 32;                             // 288*64
    float* sc2 = wt2 + 288 * 64;  float* sh2 = sc2 + 64;
    float* wt3 = sh2 + 64;                             // 576*128
    float* sc3 = wt3 + 576 * 128; float* sh3 = sc3 + 128;

    prep_kernel<32, 147><<<19, 256, 0, stream>>>(c1w, c1b, bn1g, bn1b, bn1m, bn1v, wt1, sc1, sh1);
    prep_kernel<64, 288><<<72, 256, 0, stream>>>(c2w, c2b, bn2g, bn2b, bn2m, bn2v, wt2, sc2, sh2);
    prep_kernel<128, 576><<<288, 256, 0, stream>>>(c3w, c3b, bn3g, bn3b, bn3m, bn3v, wt3, sc3, sh3);

    // conv1: M = 128*56*56 = 401408, BM=512 -> 784 blocks; OC=32 -> 1 N-block
    {
        dim3 grid(401408 / 512, 1);
        conv_gemm_kernel<3, 7, 4, 3, 224, 224, 56, 56, 32, 512, 32>
            <<<grid, 256, 0, stream>>>(x, wt1, sc1, sh1, c1o);
    }
    // conv2: M = 128*28*28 = 100352, BM=256 -> 392; OC=64 -> 1
    {
        dim3 grid(100352 / 256, 1);
        conv_gemm_kernel<32, 3, 2, 1, 56, 56, 28, 28, 64, 256, 64>
            <<<grid, 256, 0, stream>>>(c1o, wt2, sc2, sh2, c2o);
    }
    // conv3: M = 128*14*14 = 25088, BM=256 -> 98; OC=128 -> 2
    {
        dim3 grid(25088 / 256, 2);
        conv_gemm_kernel<64, 3, 2, 1, 28, 28, 14, 14, 128, 256, 64>
            <<<grid, 256, 0, stream>>>(c2o, wt3, sc3, sh3, c3o);
    }
    head_kernel<<<N, 256, 0, stream>>>(c3o, prw, prb, qw, pw1, pb1, pw2, pb2,
                                       (float*)d_out);
}

// Round 3
// 512.555 us; speedup vs baseline: 8.4607x; 3.5052x over previous
//
#include <hip/hip_runtime.h>
#include <math.h>

#define DEV __device__ __forceinline__

// ============ prep: transpose weights [OC][KT] -> [KT][OC]; fold BN ============
template<int OC, int KT>
__global__ void prep_kernel(const float* __restrict__ w,
                            const float* __restrict__ cb,
                            const float* __restrict__ bg, const float* __restrict__ bb,
                            const float* __restrict__ bm, const float* __restrict__ bv,
                            float* __restrict__ wt, float* __restrict__ scale,
                            float* __restrict__ shift)
{
    int tid = blockIdx.x * blockDim.x + threadIdx.x;
    if (tid < OC) {
        float sc = bg[tid] * rsqrtf(bv[tid] + 1e-5f);
        scale[tid] = sc;
        shift[tid] = (cb[tid] - bm[tid]) * sc + bb[tid];
    }
    int stride = gridDim.x * blockDim.x;
    for (int e = tid; e < OC * KT; e += stride) {
        int oc = e / KT, k = e % KT;
        wt[k * OC + oc] = w[e];
    }
}

// ============ implicit-GEMM conv + BN + ReLU ============
// M = N*OH*OW (spatial), N-dim = OC, K = IC*KS*KS. 8x8 register tile.
// Staging loads are lane-consecutive in m: coalesced global, conflict-free LDS.
template<int IC, int KS, int S, int P, int IH, int IW, int OH, int OW, int OC,
         int BM, int BN>
__global__ __launch_bounds__(256, 2) void conv_gemm_kernel(
    const float* __restrict__ x,      // (N,IC,IH,IW)
    const float* __restrict__ wt,     // (KT,OC) transposed weights
    const float* __restrict__ scale,  // (OC)
    const float* __restrict__ shift,  // (OC)
    float* __restrict__ out)          // (N,OC,OH,OW)
{
    constexpr int KT = IC * KS * KS;
    constexpr int BK = 8;
    constexpr int KITER = (KT + BK - 1) / BK;
    constexpr int TM = 8, TN = 8;
    constexpr int MT = BM / TM;            // 64 (conv1) or 32
    constexpr int NT = BN / TN;            // 4 (conv1) or 8
    static_assert(MT * NT == 256, "thread count");
    constexpr int MREP = BM / 256;         // m-values per thread in staging (2 or 1)
    constexpr int BELEM = (BK * BN) / 256; // B elems per thread (1 or 2)
    constexpr int OHW = OH * OW;
    static_assert(OHW % 4 == 0, "float4 store");

    __shared__ float As[BK][BM];
    __shared__ float Bs[BK][BN];

    const int tid = threadIdx.x;
    const int bm0 = blockIdx.x * BM;
    const int oc0 = blockIdx.y * BN;

    const int tmi = tid % MT;
    const int tni = tid / MT;

    // per-thread m decomposition for staging (constant across K loop)
    int a_n[MREP], a_ih0[MREP], a_iw0[MREP];
    #pragma unroll
    for (int r = 0; r < MREP; ++r) {
        int m = bm0 + r * 256 + tid;
        int n = m / OHW;
        int s = m % OHW;
        int oh = s / OW, ow = s % OW;
        a_n[r] = n;
        a_ih0[r] = oh * S - P;
        a_iw0[r] = ow * S - P;
    }

    float acc[TM][TN];
    #pragma unroll
    for (int i = 0; i < TM; ++i)
        #pragma unroll
        for (int j = 0; j < TN; ++j) acc[i][j] = 0.f;

    for (int kt = 0; kt < KITER; ++kt) {
        const int k0 = kt * BK;

        // ---- gather A (im2col), lane-consecutive m ----
        float av[BK][MREP];
        #pragma unroll
        for (int kk = 0; kk < BK; ++kk) {
            int kg = k0 + kk;
            int ic = kg / (KS * KS);
            int r2 = kg % (KS * KS);
            int kh = r2 / KS, kw = r2 % KS;
            bool kval = (KT % BK == 0) || (kg < KT);
            #pragma unroll
            for (int r = 0; r < MREP; ++r) {
                int ih = a_ih0[r] + kh;
                int iw = a_iw0[r] + kw;
                float v = 0.f;
                if (kval && ih >= 0 && ih < IH && iw >= 0 && iw < IW)
                    v = x[(((size_t)a_n[r] * IC + ic) * IH + ih) * IW + iw];
                av[kk][r] = v;
            }
        }
        // ---- gather B (transposed weights), lane-consecutive oc ----
        float bvr[BELEM];
        #pragma unroll
        for (int i = 0; i < BELEM; ++i) {
            int e = i * 256 + tid;
            int kk = e / BN, oc = e % BN;
            int kg = k0 + kk;
            bvr[i] = ((KT % BK == 0) || kg < KT) ? wt[(size_t)kg * OC + oc0 + oc] : 0.f;
        }

        __syncthreads();   // previous compute done before LDS overwrite
        #pragma unroll
        for (int kk = 0; kk < BK; ++kk)
            #pragma unroll
            for (int r = 0; r < MREP; ++r)
                As[kk][r * 256 + tid] = av[kk][r];
        #pragma unroll
        for (int i = 0; i < BELEM; ++i) {
            int e = i * 256 + tid;
            Bs[e / BN][e % BN] = bvr[i];
        }
        __syncthreads();

        // ---- 8x8 outer-product accumulate ----
        #pragma unroll
        for (int kk = 0; kk < BK; ++kk) {
            float4 alo = *(const float4*)&As[kk][tmi * 4];
            float4 ahi = *(const float4*)&As[kk][tmi * 4 + BM / 2];
            float4 blo = *(const float4*)&Bs[kk][tni * TN];
            float4 bhi = *(const float4*)&Bs[kk][tni * TN + 4];
            float a[TM] = {alo.x, alo.y, alo.z, alo.w, ahi.x, ahi.y, ahi.z, ahi.w};
            float b[TN] = {blo.x, blo.y, blo.z, blo.w, bhi.x, bhi.y, bhi.z, bhi.w};
            #pragma unroll
            for (int i = 0; i < TM; ++i)
                #pragma unroll
                for (int j = 0; j < TN; ++j)
                    acc[i][j] = fmaf(a[i], b[j], acc[i][j]);
        }
    }

    // ---- epilogue: BN + ReLU + coalesced float4 stores ----
    float sc[TN], sh[TN];
    #pragma unroll
    for (int j = 0; j < TN; ++j) {
        int oc = oc0 + tni * TN + j;
        sc[j] = scale[oc];
        sh[j] = shift[oc];
    }
    #pragma unroll
    for (int half = 0; half < 2; ++half) {
        int mbase = bm0 + half * (BM / 2) + tmi * 4;
        int n = mbase / OHW;
        int s = mbase % OHW;       // groups of 4 never cross n (OHW % 4 == 0)
        #pragma unroll
        for (int j = 0; j < TN; ++j) {
            int oc = oc0 + tni * TN + j;
            float4 v;
            v.x = fmaf(acc[half * 4 + 0][j], sc[j], sh[j]);
            v.y = fmaf(acc[half * 4 + 1][j], sc[j], sh[j]);
            v.z = fmaf(acc[half * 4 + 2][j], sc[j], sh[j]);
            v.w = fmaf(acc[half * 4 + 3][j], sc[j], sh[j]);
            v.x = v.x > 0.f ? v.x : 0.f;
            v.y = v.y > 0.f ? v.y : 0.f;
            v.z = v.z > 0.f ? v.z : 0.f;
            v.w = v.w > 0.f ? v.w : 0.f;
            *(float4*)&out[((size_t)n * OC + oc) * OHW + s] = v;
        }
    }
}

// ============ quantum gate helpers ============
DEV void gate_ry(float* re, float* im, int q, float th) {
    float c = cosf(th * 0.5f), s = sinf(th * 0.5f);
    int mask = 8 >> q;
    for (int i = 0; i < 16; ++i) {
        if (i & mask) continue;
        int j = i | mask;
        float r0 = re[i], i0 = im[i], r1 = re[j], i1 = im[j];
        re[i] = c * r0 - s * r1;  im[i] = c * i0 - s * i1;
        re[j] = s * r0 + c * r1;  im[j] = s * i0 + c * i1;
    }
}
DEV void gate_rx(float* re, float* im, int q, float th) {
    float c = cosf(th * 0.5f), s = sinf(th * 0.5f);
    int mask = 8 >> q;
    for (int i = 0; i < 16; ++i) {
        if (i & mask) continue;
        int j = i | mask;
        float r0 = re[i], i0 = im[i], r1 = re[j], i1 = im[j];
        re[i] = c * r0 + s * i1;  im[i] = c * i0 - s * r1;
        re[j] = s * i0 + c * r1;  im[j] = -s * r0 + c * i1;
    }
}
DEV void gate_rz(float* re, float* im, int q, float th) {
    float c = cosf(th * 0.5f), s = sinf(th * 0.5f);
    int mask = 8 >> q;
    for (int i = 0; i < 16; ++i) {
        float sg = (i & mask) ? s : -s;
        float r = re[i], m = im[i];
        re[i] = c * r - sg * m;
        im[i] = c * m + sg * r;
    }
}
DEV void gate_cnot(float* re, float* im, int c, int t) {
    int cm = 8 >> c, tm = 8 >> t;
    for (int i = 0; i < 16; ++i) {
        if ((i & cm) && !(i & tm)) {
            int j = i | tm;
            float r = re[i]; re[i] = re[j]; re[j] = r;
            float m = im[i]; im[i] = im[j]; im[j] = m;
        }
    }
}

// ============ fused head: pool -> linear/tanh -> circuit -> MLP ============
__global__ __launch_bounds__(256) void head_kernel(
    const float* __restrict__ conv3out,  // (N,128,14,14)
    const float* __restrict__ pre_w, const float* __restrict__ pre_b,
    const float* __restrict__ qw,
    const float* __restrict__ pw1, const float* __restrict__ pb1,
    const float* __restrict__ pw2, const float* __restrict__ pb2,
    float* __restrict__ out)             // (N,5)
{
    __shared__ float f[512];
    __shared__ float ang[4];
    __shared__ float sre[16], simg[16];
    __shared__ float zexp[4];
    __shared__ float h1[64];

    int b = blockIdx.x;
    int t = threadIdx.x;

    const float* src = conv3out + (size_t)b * 128 * 196;
    for (int p = t; p < 512; p += 256) {
        int c = p >> 2, i = (p >> 1) & 1, j = p & 1;
        const float* sp = src + c * 196 + (i * 7) * 14 + j * 7;
        float s = 0.f;
        #pragma unroll
        for (int u = 0; u < 7; ++u)
            #pragma unroll
            for (int v = 0; v < 7; ++v)
                s += sp[u * 14 + v];
        f[p] = s * (1.f / 49.f);
    }
    __syncthreads();

    int wv = t >> 6, lane = t & 63;
    float partial = 0.f;
    for (int d = lane; d < 512; d += 64)
        partial += f[d] * pre_w[wv * 512 + d];
    #pragma unroll
    for (int off = 32; off > 0; off >>= 1)
        partial += __shfl_down(partial, off, 64);
    if (lane == 0)
        ang[wv] = tanhf(partial + pre_b[wv]) * 3.14159265358979323846f;
    __syncthreads();

    if (t == 0) {
        for (int i = 0; i < 16; ++i) { sre[i] = 0.f; simg[i] = 0.f; }
        sre[0] = 1.f;
        for (int q = 0; q < 4; ++q) gate_ry(sre, simg, q, ang[q]);
        for (int l = 0; l < 2; ++l) {
            for (int q = 0; q < 4; ++q) {
                const float* qq = qw + (l * 4 + q) * 3;
                gate_rx(sre, simg, q, qq[0]);
                gate_ry(sre, simg, q, qq[1]);
                gate_rz(sre, simg, q, qq[2]);
            }
            gate_cnot(sre, simg, 0, 1);
            gate_cnot(sre, simg, 1, 2);
            gate_cnot(sre, simg, 2, 3);
            gate_cnot(sre, simg, 3, 0);
        }
        for (int q = 0; q < 4; ++q) {
            float z = 0.f;
            for (int i = 0; i < 16; ++i) {
                float p2 = sre[i] * sre[i] + simg[i] * simg[i];
                z += (((i >> (3 - q)) & 1) ? -p2 : p2);
            }
            zexp[q] = z;
        }
    }
    __syncthreads();

    if (t < 64) {
        float s = pb1[t];
        #pragma unroll
        for (int k = 0; k < 4; ++k) s += zexp[k] * pw1[t * 4 + k];
        h1[t] = s > 0.f ? s : 0.f;
    }
    __syncthreads();

    if (t < 5) {
        float s = pb2[t];
        for (int k = 0; k < 64; ++k) s += h1[k] * pw2[t * 64 + k];
        out[b * 5 + t] = s;
    }
}

extern "C" void kernel_launch(void* const* d_in, const int* in_sizes, int n_in,
                              void* d_out, int out_size, void* d_ws, size_t ws_size,
                              hipStream_t stream) {
    const float* x    = (const float*)d_in[0];
    const float* c1w  = (const float*)d_in[1];
    const float* c1b  = (const float*)d_in[2];
    const float* bn1g = (const float*)d_in[3];
    const float* bn1b = (const float*)d_in[4];
    const float* bn1m = (const float*)d_in[5];
    const float* bn1v = (const float*)d_in[6];
    const float* c2w  = (const float*)d_in[7];
    const float* c2b  = (const float*)d_in[8];
    const float* bn2g = (const float*)d_in[9];
    const float* bn2b = (const float*)d_in[10];
    const float* bn2m = (const float*)d_in[11];
    const float* bn2v = (const float*)d_in[12];
    const float* c3w  = (const float*)d_in[13];
    const float* c3b  = (const float*)d_in[14];
    const float* bn3g = (const float*)d_in[15];
    const float* bn3b = (const float*)d_in[16];
    const float* bn3m = (const float*)d_in[17];
    const float* bn3v = (const float*)d_in[18];
    const float* prw  = (const float*)d_in[19];
    const float* prb  = (const float*)d_in[20];
    const float* qw   = (const float*)d_in[21];
    const float* pw1  = (const float*)d_in[22];
    const float* pb1  = (const float*)d_in[23];
    const float* pw2  = (const float*)d_in[24];
    const float* pb2  = (const float*)d_in[25];

    const int N = in_sizes[0] / (3 * 224 * 224);   // 128

    // workspace layout (floats)
    float* c1o = (float*)d_ws;                         // N*32*56*56
    float* c2o = c1o + (size_t)N * 32 * 56 * 56;       // N*64*28*28
    float* c3o = c2o + (size_t)N * 64 * 28 * 28;       // N*128*14*14
    float* wt1 = c3o + (size_t)N * 128 * 14 * 14;      // 147*32
    float* sc1 = wt1 + 147 * 32;  float* sh1 = sc1 + 32;
    float* wt2 = sh1 + 32;                             // 288*64
    float* sc2 = wt2 + 288 * 64;  float* sh2 = sc2 + 64;
    float* wt3 = sh2 + 64;                             // 576*128
    float* sc3 = wt3 + 576 * 128; float* sh3 = sc3 + 128;

    prep_kernel<32, 147><<<19, 256, 0, stream>>>(c1w, c1b, bn1g, bn1b, bn1m, bn1v, wt1, sc1, sh1);
    prep_kernel<64, 288><<<72, 256, 0, stream>>>(c2w, c2b, bn2g, bn2b, bn2m, bn2v, wt2, sc2, sh2);
    prep_kernel<128, 576><<<288, 256, 0, stream>>>(c3w, c3b, bn3g, bn3b, bn3m, bn3v, wt3, sc3, sh3);

    // conv1: M = 128*56*56 = 401408, BM=512 -> 784 blocks; OC=32 -> 1 N-block
    {
        dim3 grid(401408 / 512, 1);
        conv_gemm_kernel<3, 7, 4, 3, 224, 224, 56, 56, 32, 512, 32>
            <<<grid, 256, 0, stream>>>(x, wt1, sc1, sh1, c1o);
    }
    // conv2: M = 128*28*28 = 100352, BM=256 -> 392; OC=64 -> 1
    {
        dim3 grid(100352 / 256, 1);
        conv_gemm_kernel<32, 3, 2, 1, 56, 56, 28, 28, 64, 256, 64>
            <<<grid, 256, 0, stream>>>(c1o, wt2, sc2, sh2, c2o);
    }
    // conv3: M = 128*14*14 = 25088, BM=256 -> 98; OC=128 -> 2
    {
        dim3 grid(25088 / 256, 2);
        conv_gemm_kernel<64, 3, 2, 1, 28, 28, 14, 14, 128, 256, 64>
            <<<grid, 256, 0, stream>>>(c2o, wt3, sc3, sh3, c3o);
    }
    head_kernel<<<N, 256, 0, stream>>>(c3o, prw, prb, qw, pw1, pb1, pw2, pb2,
                                       (float*)d_out);
}

// Round 4
// 483.711 us; speedup vs baseline: 8.9652x; 1.0596x over previous
//
#include <hip/hip_runtime.h>
#include <math.h>

#define DEV __device__ __forceinline__

// ============ prep: transpose weights [OC][KT] -> [KT][OC]; fold BN ============
template<int OC, int KT>
__global__ void prep_kernel(const float* __restrict__ w,
                            const float* __restrict__ cb,
                            const float* __restrict__ bg, const float* __restrict__ bb,
                            const float* __restrict__ bm, const float* __restrict__ bv,
                            float* __restrict__ wt, float* __restrict__ scale,
                            float* __restrict__ shift)
{
    int tid = blockIdx.x * blockDim.x + threadIdx.x;
    if (tid < OC) {
        float sc = bg[tid] * rsqrtf(bv[tid] + 1e-5f);
        scale[tid] = sc;
        shift[tid] = (cb[tid] - bm[tid]) * sc + bb[tid];
    }
    int stride = gridDim.x * blockDim.x;
    for (int e = tid; e < OC * KT; e += stride) {
        int oc = e / KT, k = e % KT;
        wt[k * OC + oc] = w[e];
    }
}

// ============ implicit-GEMM conv (+ optional BN/ReLU epilogue) ============
// M = N*OH*OW, N-dim = OC, K = IC*KS*KS. TMxTN register tile, 256 threads.
// blockIdx.z = K-split chunk; EPI=false stores raw partial sums (consumer folds BN).
template<int IC, int KS, int S, int P, int IH, int IW, int OH, int OW, int OC,
         int BM, int BN, int TM, int TN, int KCH, bool EPI, int MINW>
__global__ __launch_bounds__(256, MINW) void conv_gemm_kernel(
    const float* __restrict__ x,      // (N,IC,IH,IW)
    const float* __restrict__ wt,     // (KT,OC) transposed weights
    const float* __restrict__ scale,  // (OC)
    const float* __restrict__ shift,  // (OC)
    float* __restrict__ out,          // (N,OC,OH,OW) [+ z*batchN*OC*OHW]
    int batchN)
{
    constexpr int KT = IC * KS * KS;
    constexpr int BK = 8;
    constexpr int KITER = (KCH + BK - 1) / BK;
    constexpr int MT = BM / TM;
    constexpr int NT = BN / TN;
    static_assert(MT * NT == 256, "thread count");
    constexpr int AELEM = BK * BM / 256;
    constexpr int BELEM = BK * BN / 256;
    constexpr int MD = (BM > 256) ? BM / 256 : 1;   // distinct m per thread
    constexpr int BMOD = (BM < 256) ? BM : 256;
    constexpr int OHW = OH * OW;
    constexpr int AH = TM / 4;
    static_assert(OHW % 4 == 0, "float4 store");

    __shared__ float As[BK][BM];
    __shared__ float Bs[BK][BN];

    const int tid = threadIdx.x;
    const int bm0 = blockIdx.x * BM;
    const int oc0 = blockIdx.y * BN;
    const int kz0 = blockIdx.z * KCH;
    float* outp = out + (size_t)blockIdx.z * ((size_t)batchN * OC * OHW);

    const int tmi = tid % MT;
    const int tni = tid / MT;

    // per-thread m decomposition for staging (constant across K loop)
    int a_n[MD], a_ih0[MD], a_iw0[MD];
    #pragma unroll
    for (int r = 0; r < MD; ++r) {
        int m = bm0 + r * 256 + (tid % BMOD);
        int n = m / OHW;
        int s = m % OHW;
        int oh = s / OW, ow = s % OW;
        a_n[r] = n;
        a_ih0[r] = oh * S - P;
        a_iw0[r] = ow * S - P;
    }

    float acc[TM][TN];
    #pragma unroll
    for (int i = 0; i < TM; ++i)
        #pragma unroll
        for (int j = 0; j < TN; ++j) acc[i][j] = 0.f;

    for (int kt = 0; kt < KITER; ++kt) {
        const int k0 = kz0 + kt * BK;

        // ---- gather A (im2col), lane-consecutive m ----
        float av[AELEM];
        #pragma unroll
        for (int i = 0; i < AELEM; ++i) {
            int e = i * 256 + tid;
            int kk = e / BM;
            int ml = e % BM;
            int r = ml >> 8;                 // 0 when BM<=256
            int kg = k0 + kk;
            int ic = kg / (KS * KS);
            int r2 = kg % (KS * KS);
            int kh = r2 / KS, kw = r2 % KS;
            int ih = a_ih0[r] + kh;
            int iw = a_iw0[r] + kw;
            bool ok = ((KT % BK == 0) || kg < KT) &&
                      ih >= 0 && ih < IH && iw >= 0 && iw < IW;
            av[i] = ok ? x[(((size_t)a_n[r] * IC + ic) * IH + ih) * IW + iw] : 0.f;
        }
        // ---- gather B (transposed weights), lane-consecutive oc ----
        float bvr[BELEM];
        #pragma unroll
        for (int i = 0; i < BELEM; ++i) {
            int e = i * 256 + tid;
            int kk = e / BN;
            int kg = k0 + kk;
            bvr[i] = ((KT % BK == 0) || kg < KT) ? wt[(size_t)kg * OC + oc0 + (e % BN)]
                                                 : 0.f;
        }

        __syncthreads();
        #pragma unroll
        for (int i = 0; i < AELEM; ++i) {
            int e = i * 256 + tid;
            As[e / BM][e % BM] = av[i];
        }
        #pragma unroll
        for (int i = 0; i < BELEM; ++i) {
            int e = i * 256 + tid;
            Bs[e / BN][e % BN] = bvr[i];
        }
        __syncthreads();

        // ---- TMxTN outer-product accumulate ----
        #pragma unroll
        for (int kk = 0; kk < BK; ++kk) {
            float a[TM], b[TN];
            #pragma unroll
            for (int h = 0; h < AH; ++h) {
                float4 f4 = *(const float4*)&As[kk][tmi * 4 + h * (BM / AH)];
                a[h * 4 + 0] = f4.x; a[h * 4 + 1] = f4.y;
                a[h * 4 + 2] = f4.z; a[h * 4 + 3] = f4.w;
            }
            #pragma unroll
            for (int h = 0; h < TN / 4; ++h) {
                float4 f4 = *(const float4*)&Bs[kk][tni * TN + h * 4];
                b[h * 4 + 0] = f4.x; b[h * 4 + 1] = f4.y;
                b[h * 4 + 2] = f4.z; b[h * 4 + 3] = f4.w;
            }
            #pragma unroll
            for (int i = 0; i < TM; ++i)
                #pragma unroll
                for (int j = 0; j < TN; ++j)
                    acc[i][j] = fmaf(a[i], b[j], acc[i][j]);
        }
    }

    // ---- epilogue ----
    float sc[TN], sh[TN];
    if (EPI) {
        #pragma unroll
        for (int j = 0; j < TN; ++j) {
            int oc = oc0 + tni * TN + j;
            sc[j] = scale[oc];
            sh[j] = shift[oc];
        }
    }
    #pragma unroll
    for (int h = 0; h < AH; ++h) {
        int mbase = bm0 + h * (BM / AH) + tmi * 4;
        int n = mbase / OHW;
        int s = mbase % OHW;       // groups of 4 never cross n (OHW % 4 == 0)
        #pragma unroll
        for (int j = 0; j < TN; ++j) {
            int oc = oc0 + tni * TN + j;
            float4 v;
            v.x = acc[h * 4 + 0][j];
            v.y = acc[h * 4 + 1][j];
            v.z = acc[h * 4 + 2][j];
            v.w = acc[h * 4 + 3][j];
            if (EPI) {
                v.x = fmaf(v.x, sc[j], sh[j]); v.x = v.x > 0.f ? v.x : 0.f;
                v.y = fmaf(v.y, sc[j], sh[j]); v.y = v.y > 0.f ? v.y : 0.f;
                v.z = fmaf(v.z, sc[j], sh[j]); v.z = v.z > 0.f ? v.z : 0.f;
                v.w = fmaf(v.w, sc[j], sh[j]); v.w = v.w > 0.f ? v.w : 0.f;
            }
            *(float4*)&outp[((size_t)n * OC + oc) * OHW + s] = v;
        }
    }
}

// ============ quantum gate helpers ============
DEV void gate_ry(float* re, float* im, int q, float th) {
    float c = cosf(th * 0.5f), s = sinf(th * 0.5f);
    int mask = 8 >> q;
    for (int i = 0; i < 16; ++i) {
        if (i & mask) continue;
        int j = i | mask;
        float r0 = re[i], i0 = im[i], r1 = re[j], i1 = im[j];
        re[i] = c * r0 - s * r1;  im[i] = c * i0 - s * i1;
        re[j] = s * r0 + c * r1;  im[j] = s * i0 + c * i1;
    }
}
DEV void gate_rx(float* re, float* im, int q, float th) {
    float c = cosf(th * 0.5f), s = sinf(th * 0.5f);
    int mask = 8 >> q;
    for (int i = 0; i < 16; ++i) {
        if (i & mask) continue;
        int j = i | mask;
        float r0 = re[i], i0 = im[i], r1 = re[j], i1 = im[j];
        re[i] = c * r0 + s * i1;  im[i] = c * i0 - s * r1;
        re[j] = s * i0 + c * r1;  im[j] = -s * r0 + c * i1;
    }
}
DEV void gate_rz(float* re, float* im, int q, float th) {
    float c = cosf(th * 0.5f), s = sinf(th * 0.5f);
    int mask = 8 >> q;
    for (int i = 0; i < 16; ++i) {
        float sg = (i & mask) ? s : -s;
        float r = re[i], m = im[i];
        re[i] = c * r - sg * m;
        im[i] = c * m + sg * r;
    }
}
DEV void gate_cnot(float* re, float* im, int c, int t) {
    int cm = 8 >> c, tm = 8 >> t;
    for (int i = 0; i < 16; ++i) {
        if ((i & cm) && !(i & tm)) {
            int j = i | tm;
            float r = re[i]; re[i] = re[j]; re[j] = r;
            float m = im[i]; im[i] = im[j]; im[j] = m;
        }
    }
}

// ============ fused head: BN3+ReLU+pool -> linear/tanh -> circuit -> MLP ============
__global__ __launch_bounds__(256) void head_kernel(
    const float* __restrict__ p3a,       // (N,128,14,14) raw partial (K 0..287)
    const float* __restrict__ p3b,       // (N,128,14,14) raw partial (K 288..575)
    const float* __restrict__ sc3, const float* __restrict__ sh3,
    const float* __restrict__ pre_w, const float* __restrict__ pre_b,
    const float* __restrict__ qw,
    const float* __restrict__ pw1, const float* __restrict__ pb1,
    const float* __restrict__ pw2, const float* __restrict__ pb2,
    float* __restrict__ out)             // (N,5)
{
    __shared__ float f[512];
    __shared__ float ang[4];
    __shared__ float sre[16], simg[16];
    __shared__ float zexp[4];
    __shared__ float h1[64];

    int b = blockIdx.x;
    int t = threadIdx.x;

    size_t boff = (size_t)b * 128 * 196;
    for (int p = t; p < 512; p += 256) {
        int c = p >> 2, i = (p >> 1) & 1, j = p & 1;
        size_t base = boff + c * 196 + (i * 7) * 14 + j * 7;
        float scl = sc3[c], shf = sh3[c];
        float s = 0.f;
        #pragma unroll
        for (int u = 0; u < 7; ++u)
            #pragma unroll
            for (int v = 0; v < 7; ++v) {
                size_t idx = base + u * 14 + v;
                float val = fmaf(p3a[idx] + p3b[idx], scl, shf);
                s += val > 0.f ? val : 0.f;
            }
        f[p] = s * (1.f / 49.f);
    }
    __syncthreads();

    int wv = t >> 6, lane = t & 63;
    float partial = 0.f;
    for (int d = lane; d < 512; d += 64)
        partial += f[d] * pre_w[wv * 512 + d];
    #pragma unroll
    for (int off = 32; off > 0; off >>= 1)
        partial += __shfl_down(partial, off, 64);
    if (lane == 0)
        ang[wv] = tanhf(partial + pre_b[wv]) * 3.14159265358979323846f;
    __syncthreads();

    if (t == 0) {
        for (int i = 0; i < 16; ++i) { sre[i] = 0.f; simg[i] = 0.f; }
        sre[0] = 1.f;
        for (int q = 0; q < 4; ++q) gate_ry(sre, simg, q, ang[q]);
        for (int l = 0; l < 2; ++l) {
            for (int q = 0; q < 4; ++q) {
                const float* qq = qw + (l * 4 + q) * 3;
                gate_rx(sre, simg, q, qq[0]);
                gate_ry(sre, simg, q, qq[1]);
                gate_rz(sre, simg, q, qq[2]);
            }
            gate_cnot(sre, simg, 0, 1);
            gate_cnot(sre, simg, 1, 2);
            gate_cnot(sre, simg, 2, 3);
            gate_cnot(sre, simg, 3, 0);
        }
        for (int q = 0; q < 4; ++q) {
            float z = 0.f;
            for (int i = 0; i < 16; ++i) {
                float p2 = sre[i] * sre[i] + simg[i] * simg[i];
                z += (((i >> (3 - q)) & 1) ? -p2 : p2);
            }
            zexp[q] = z;
        }
    }
    __syncthreads();

    if (t < 64) {
        float s = pb1[t];
        #pragma unroll
        for (int k = 0; k < 4; ++k) s += zexp[k] * pw1[t * 4 + k];
        h1[t] = s > 0.f ? s : 0.f;
    }
    __syncthreads();

    if (t < 5) {
        float s = pb2[t];
        for (int k = 0; k < 64; ++k) s += h1[k] * pw2[t * 64 + k];
        out[b * 5 + t] = s;
    }
}

extern "C" void kernel_launch(void* const* d_in, const int* in_sizes, int n_in,
                              void* d_out, int out_size, void* d_ws, size_t ws_size,
                              hipStream_t stream) {
    const float* x    = (const float*)d_in[0];
    const float* c1w  = (const float*)d_in[1];
    const float* c1b  = (const float*)d_in[2];
    const float* bn1g = (const float*)d_in[3];
    const float* bn1b = (const float*)d_in[4];
    const float* bn1m = (const float*)d_in[5];
    const float* bn1v = (const float*)d_in[6];
    const float* c2w  = (const float*)d_in[7];
    const float* c2b  = (const float*)d_in[8];
    const float* bn2g = (const float*)d_in[9];
    const float* bn2b = (const float*)d_in[10];
    const float* bn2m = (const float*)d_in[11];
    const float* bn2v = (const float*)d_in[12];
    const float* c3w  = (const float*)d_in[13];
    const float* c3bi = (const float*)d_in[14];
    const float* bn3g = (const float*)d_in[15];
    const float* bn3b = (const float*)d_in[16];
    const float* bn3m = (const float*)d_in[17];
    const float* bn3v = (const float*)d_in[18];
    const float* prw  = (const float*)d_in[19];
    const float* prb  = (const float*)d_in[20];
    const float* qw   = (const float*)d_in[21];
    const float* pw1  = (const float*)d_in[22];
    const float* pb1  = (const float*)d_in[23];
    const float* pw2  = (const float*)d_in[24];
    const float* pb2  = (const float*)d_in[25];

    const int N = in_sizes[0] / (3 * 224 * 224);   // 128

    // workspace layout (floats)
    float* c1o = (float*)d_ws;                         // N*32*56*56 = 12,845,056
    float* c2o = c1o + (size_t)N * 32 * 56 * 56;       // N*64*28*28 =  6,422,528
    float* wt1 = c2o + (size_t)N * 64 * 28 * 28;       // 147*32
    float* sc1 = wt1 + 147 * 32;  float* sh1 = sc1 + 32;
    float* wt2 = sh1 + 32;                             // 288*64
    float* sc2 = wt2 + 288 * 64;  float* sh2 = sc2 + 64;
    float* wt3 = sh2 + 64;                             // 576*128
    float* sc3 = wt3 + 576 * 128; float* sh3 = sc3 + 128;
    // conv3 split-K partials alias the (dead after conv2) c1o region:
    float* p3a = c1o;                                  // N*128*14*14 = 3,211,264
    float* p3b = c1o + (size_t)N * 128 * 14 * 14;

    prep_kernel<32, 147><<<19, 256, 0, stream>>>(c1w, c1b, bn1g, bn1b, bn1m, bn1v, wt1, sc1, sh1);
    prep_kernel<64, 288><<<72, 256, 0, stream>>>(c2w, c2b, bn2g, bn2b, bn2m, bn2v, wt2, sc2, sh2);
    prep_kernel<128, 576><<<288, 256, 0, stream>>>(c3w, c3bi, bn3g, bn3b, bn3m, bn3v, wt3, sc3, sh3);

    // conv1: M=401408, BM=512 -> 784 blocks, 8x8 tile
    conv_gemm_kernel<3, 7, 4, 3, 224, 224, 56, 56, 32, 512, 32, 8, 8, 147, true, 3>
        <<<dim3(401408 / 512, 1, 1), 256, 0, stream>>>(x, wt1, sc1, sh1, c1o, N);
    // conv2: M=100352, BM=128 -> 784 blocks, 4x8 tile
    conv_gemm_kernel<32, 3, 2, 1, 56, 56, 28, 28, 64, 128, 64, 4, 8, 288, true, 4>
        <<<dim3(100352 / 128, 1, 1), 256, 0, stream>>>(c1o, wt2, sc2, sh2, c2o, N);
    // conv3: M=25088, BM=128, split-K x2 -> 196*2*2 = 784 blocks, raw partials
    conv_gemm_kernel<64, 3, 2, 1, 28, 28, 14, 14, 128, 128, 64, 4, 8, 288, false, 4>
        <<<dim3(25088 / 128, 2, 2), 256, 0, stream>>>(c2o, wt3, sc3, sh3, p3a, N);

    head_kernel<<<N, 256, 0, stream>>>(p3a, p3b, sc3, sh3, prw, prb, qw,
                                       pw1, pb1, pw2, pb2, (float*)d_out);
}

// Round 5
// 426.198 us; speedup vs baseline: 10.1750x; 1.1349x over previous
//
#include <hip/hip_runtime.h>
#include <math.h>

#define DEV __device__ __forceinline__

// ============ prep: transpose weights [OC][KT] -> [KT][OC]; fold BN ============
template<int OC, int KT>
__global__ void prep_kernel(const float* __restrict__ w,
                            const float* __restrict__ cb,
                            const float* __restrict__ bg, const float* __restrict__ bb,
                            const float* __restrict__ bm, const float* __restrict__ bv,
                            float* __restrict__ wt, float* __restrict__ scale,
                            float* __restrict__ shift)
{
    int tid = blockIdx.x * blockDim.x + threadIdx.x;
    if (tid < OC) {
        float sc = bg[tid] * rsqrtf(bv[tid] + 1e-5f);
        scale[tid] = sc;
        shift[tid] = (cb[tid] - bm[tid]) * sc + bb[tid];
    }
    int stride = gridDim.x * blockDim.x;
    for (int e = tid; e < OC * KT; e += stride) {
        int oc = e / KT, k = e % KT;
        wt[k * OC + oc] = w[e];
    }
}

// ============ implicit-GEMM conv (+ optional BN/ReLU epilogue) ============
// M = N*OH*OW, N-dim = OC, K = IC*KS*KS. TMxTN register tile, 256 threads.
// blockIdx.z = K-split chunk; EPI=false stores raw partial sums (consumer folds BN).
template<int IC, int KS, int S, int P, int IH, int IW, int OH, int OW, int OC,
         int BM, int BN, int TM, int TN, int KCH, bool EPI, int MINW>
__global__ __launch_bounds__(256, MINW) void conv_gemm_kernel(
    const float* __restrict__ x,      // (N,IC,IH,IW)
    const float* __restrict__ wt,     // (KT,OC) transposed weights
    const float* __restrict__ scale,  // (OC)
    const float* __restrict__ shift,  // (OC)
    float* __restrict__ out,          // (N,OC,OH,OW) [+ z*batchN*OC*OHW]
    int batchN)
{
    constexpr int KT = IC * KS * KS;
    constexpr int BK = 8;
    constexpr int KITER = (KCH + BK - 1) / BK;
    constexpr int MT = BM / TM;
    constexpr int NT = BN / TN;
    static_assert(MT * NT == 256, "thread count");
    constexpr int AELEM = BK * BM / 256;
    constexpr int BELEM = BK * BN / 256;
    constexpr int MD = (BM > 256) ? BM / 256 : 1;   // distinct m per thread
    constexpr int BMOD = (BM < 256) ? BM : 256;
    constexpr int OHW = OH * OW;
    constexpr int AH = TM / 4;
    static_assert(OHW % 4 == 0, "float4 store");

    __shared__ float As[BK][BM];
    __shared__ float Bs[BK][BN];

    const int tid = threadIdx.x;
    const int bm0 = blockIdx.x * BM;
    const int oc0 = blockIdx.y * BN;
    const int kz0 = blockIdx.z * KCH;
    float* outp = out + (size_t)blockIdx.z * ((size_t)batchN * OC * OHW);

    const int tmi = tid % MT;
    const int tni = tid / MT;

    // per-thread m decomposition for staging (constant across K loop)
    int a_n[MD], a_ih0[MD], a_iw0[MD];
    #pragma unroll
    for (int r = 0; r < MD; ++r) {
        int m = bm0 + r * 256 + (tid % BMOD);
        int n = m / OHW;
        int s = m % OHW;
        int oh = s / OW, ow = s % OW;
        a_n[r] = n;
        a_ih0[r] = oh * S - P;
        a_iw0[r] = ow * S - P;
    }

    float acc[TM][TN];
    #pragma unroll
    for (int i = 0; i < TM; ++i)
        #pragma unroll
        for (int j = 0; j < TN; ++j) acc[i][j] = 0.f;

    for (int kt = 0; kt < KITER; ++kt) {
        const int k0 = kz0 + kt * BK;

        // ---- gather A (im2col), lane-consecutive m ----
        float av[AELEM];
        #pragma unroll
        for (int i = 0; i < AELEM; ++i) {
            int e = i * 256 + tid;
            int kk = e / BM;
            int ml = e % BM;
            int r = ml >> 8;                 // 0 when BM<=256
            int kg = k0 + kk;
            int ic = kg / (KS * KS);
            int r2 = kg % (KS * KS);
            int kh = r2 / KS, kw = r2 % KS;
            int ih = a_ih0[r] + kh;
            int iw = a_iw0[r] + kw;
            bool ok = ((KT % BK == 0) || kg < KT) &&
                      ih >= 0 && ih < IH && iw >= 0 && iw < IW;
            av[i] = ok ? x[(((size_t)a_n[r] * IC + ic) * IH + ih) * IW + iw] : 0.f;
        }
        // ---- gather B (transposed weights), lane-consecutive oc ----
        float bvr[BELEM];
        #pragma unroll
        for (int i = 0; i < BELEM; ++i) {
            int e = i * 256 + tid;
            int kk = e / BN;
            int kg = k0 + kk;
            bvr[i] = ((KT % BK == 0) || kg < KT) ? wt[(size_t)kg * OC + oc0 + (e % BN)]
                                                 : 0.f;
        }

        __syncthreads();
        #pragma unroll
        for (int i = 0; i < AELEM; ++i) {
            int e = i * 256 + tid;
            As[e / BM][e % BM] = av[i];
        }
        #pragma unroll
        for (int i = 0; i < BELEM; ++i) {
            int e = i * 256 + tid;
            Bs[e / BN][e % BN] = bvr[i];
        }
        __syncthreads();

        // ---- TMxTN outer-product accumulate ----
        #pragma unroll
        for (int kk = 0; kk < BK; ++kk) {
            float a[TM], b[TN];
            #pragma unroll
            for (int h = 0; h < AH; ++h) {
                float4 f4 = *(const float4*)&As[kk][tmi * 4 + h * (BM / AH)];
                a[h * 4 + 0] = f4.x; a[h * 4 + 1] = f4.y;
                a[h * 4 + 2] = f4.z; a[h * 4 + 3] = f4.w;
            }
            #pragma unroll
            for (int h = 0; h < TN / 4; ++h) {
                float4 f4 = *(const float4*)&Bs[kk][tni * TN + h * 4];
                b[h * 4 + 0] = f4.x; b[h * 4 + 1] = f4.y;
                b[h * 4 + 2] = f4.z; b[h * 4 + 3] = f4.w;
            }
            #pragma unroll
            for (int i = 0; i < TM; ++i)
                #pragma unroll
                for (int j = 0; j < TN; ++j)
                    acc[i][j] = fmaf(a[i], b[j], acc[i][j]);
        }
    }

    // ---- epilogue ----
    float sc[TN], sh[TN];
    if (EPI) {
        #pragma unroll
        for (int j = 0; j < TN; ++j) {
            int oc = oc0 + tni * TN + j;
            sc[j] = scale[oc];
            sh[j] = shift[oc];
        }
    }
    #pragma unroll
    for (int h = 0; h < AH; ++h) {
        int mbase = bm0 + h * (BM / AH) + tmi * 4;
        int n = mbase / OHW;
        int s = mbase % OHW;       // groups of 4 never cross n (OHW % 4 == 0)
        #pragma unroll
        for (int j = 0; j < TN; ++j) {
            int oc = oc0 + tni * TN + j;
            float4 v;
            v.x = acc[h * 4 + 0][j];
            v.y = acc[h * 4 + 1][j];
            v.z = acc[h * 4 + 2][j];
            v.w = acc[h * 4 + 3][j];
            if (EPI) {
                v.x = fmaf(v.x, sc[j], sh[j]); v.x = v.x > 0.f ? v.x : 0.f;
                v.y = fmaf(v.y, sc[j], sh[j]); v.y = v.y > 0.f ? v.y : 0.f;
                v.z = fmaf(v.z, sc[j], sh[j]); v.z = v.z > 0.f ? v.z : 0.f;
                v.w = fmaf(v.w, sc[j], sh[j]); v.w = v.w > 0.f ? v.w : 0.f;
            }
            *(float4*)&outp[((size_t)n * OC + oc) * OHW + s] = v;
        }
    }
}

// ============ quantum gate helpers ============
DEV void gate_ry(float* re, float* im, int q, float th) {
    float c = cosf(th * 0.5f), s = sinf(th * 0.5f);
    int mask = 8 >> q;
    for (int i = 0; i < 16; ++i) {
        if (i & mask) continue;
        int j = i | mask;
        float r0 = re[i], i0 = im[i], r1 = re[j], i1 = im[j];
        re[i] = c * r0 - s * r1;  im[i] = c * i0 - s * i1;
        re[j] = s * r0 + c * r1;  im[j] = s * i0 + c * i1;
    }
}
DEV void gate_rx(float* re, float* im, int q, float th) {
    float c = cosf(th * 0.5f), s = sinf(th * 0.5f);
    int mask = 8 >> q;
    for (int i = 0; i < 16; ++i) {
        if (i & mask) continue;
        int j = i | mask;
        float r0 = re[i], i0 = im[i], r1 = re[j], i1 = im[j];
        re[i] = c * r0 + s * i1;  im[i] = c * i0 - s * r1;
        re[j] = s * i0 + c * r1;  im[j] = -s * r0 + c * i1;
    }
}
DEV void gate_rz(float* re, float* im, int q, float th) {
    float c = cosf(th * 0.5f), s = sinf(th * 0.5f);
    int mask = 8 >> q;
    for (int i = 0; i < 16; ++i) {
        float sg = (i & mask) ? s : -s;
        float r = re[i], m = im[i];
        re[i] = c * r - sg * m;
        im[i] = c * m + sg * r;
    }
}
DEV void gate_cnot(float* re, float* im, int c, int t) {
    int cm = 8 >> c, tm = 8 >> t;
    for (int i = 0; i < 16; ++i) {
        if ((i & cm) && !(i & tm)) {
            int j = i | tm;
            float r = re[i]; re[i] = re[j]; re[j] = r;
            float m = im[i]; im[i] = im[j]; im[j] = m;
        }
    }
}

// ============ fused head: BN3+ReLU+pool -> linear/tanh -> circuit -> MLP ============
__global__ __launch_bounds__(256) void head_kernel(
    const float* __restrict__ p3a,       // (N,128,14,14) raw partial (K 0..287)
    const float* __restrict__ p3b,       // (N,128,14,14) raw partial (K 288..575)
    const float* __restrict__ sc3, const float* __restrict__ sh3,
    const float* __restrict__ pre_w, const float* __restrict__ pre_b,
    const float* __restrict__ qw,
    const float* __restrict__ pw1, const float* __restrict__ pb1,
    const float* __restrict__ pw2, const float* __restrict__ pb2,
    float* __restrict__ out)             // (N,5)
{
    __shared__ float f[512];
    __shared__ float ang[4];
    __shared__ float sre[16], simg[16];
    __shared__ float zexp[4];
    __shared__ float h1[64];

    int b = blockIdx.x;
    int t = threadIdx.x;

    size_t boff = (size_t)b * 128 * 196;
    for (int p = t; p < 512; p += 256) {
        int c = p >> 2, i = (p >> 1) & 1, j = p & 1;
        size_t base = boff + c * 196 + (i * 7) * 14 + j * 7;
        float scl = sc3[c], shf = sh3[c];
        float s = 0.f;
        #pragma unroll
        for (int u = 0; u < 7; ++u)
            #pragma unroll
            for (int v = 0; v < 7; ++v) {
                size_t idx = base + u * 14 + v;
                float val = fmaf(p3a[idx] + p3b[idx], scl, shf);
                s += val > 0.f ? val : 0.f;
            }
        f[p] = s * (1.f / 49.f);
    }
    __syncthreads();

    int wv = t >> 6, lane = t & 63;
    float partial = 0.f;
    for (int d = lane; d < 512; d += 64)
        partial += f[d] * pre_w[wv * 512 + d];
    #pragma unroll
    for (int off = 32; off > 0; off >>= 1)
        partial += __shfl_down(partial, off, 64);
    if (lane == 0)
        ang[wv] = tanhf(partial + pre_b[wv]) * 3.14159265358979323846f;
    __syncthreads();

    if (t == 0) {
        for (int i = 0; i < 16; ++i) { sre[i] = 0.f; simg[i] = 0.f; }
        sre[0] = 1.f;
        for (int q = 0; q < 4; ++q) gate_ry(sre, simg, q, ang[q]);
        for (int l = 0; l < 2; ++l) {
            for (int q = 0; q < 4; ++q) {
                const float* qq = qw + (l * 4 + q) * 3;
                gate_rx(sre, simg, q, qq[0]);
                gate_ry(sre, simg, q, qq[1]);
                gate_rz(sre, simg, q, qq[2]);
            }
            gate_cnot(sre, simg, 0, 1);
            gate_cnot(sre, simg, 1, 2);
            gate_cnot(sre, simg, 2, 3);
            gate_cnot(sre, simg, 3, 0);
        }
        for (int q = 0; q < 4; ++q) {
            float z = 0.f;
            for (int i = 0; i < 16; ++i) {
                float p2 = sre[i] * sre[i] + simg[i] * simg[i];
                z += (((i >> (3 - q)) & 1) ? -p2 : p2);
            }
            zexp[q] = z;
        }
    }
    __syncthreads();

    if (t < 64) {
        float s = pb1[t];
        #pragma unroll
        for (int k = 0; k < 4; ++k) s += zexp[k] * pw1[t * 4 + k];
        h1[t] = s > 0.f ? s : 0.f;
    }
    __syncthreads();

    if (t < 5) {
        float s = pb2[t];
        for (int k = 0; k < 64; ++k) s += h1[k] * pw2[t * 64 + k];
        out[b * 5 + t] = s;
    }
}

extern "C" void kernel_launch(void* const* d_in, const int* in_sizes, int n_in,
                              void* d_out, int out_size, void* d_ws, size_t ws_size,
                              hipStream_t stream) {
    const float* x    = (const float*)d_in[0];
    const float* c1w  = (const float*)d_in[1];
    const float* c1b  = (const float*)d_in[2];
    const float* bn1g = (const float*)d_in[3];
    const float* bn1b = (const float*)d_in[4];
    const float* bn1m = (const float*)d_in[5];
    const float* bn1v = (const float*)d_in[6];
    const float* c2w  = (const float*)d_in[7];
    const float* c2b  = (const float*)d_in[8];
    const float* bn2g = (const float*)d_in[9];
    const float* bn2b = (const float*)d_in[10];
    const float* bn2m = (const float*)d_in[11];
    const float* bn2v = (const float*)d_in[12];
    const float* c3w  = (const float*)d_in[13];
    const float* c3bi = (const float*)d_in[14];
    const float* bn3g = (const float*)d_in[15];
    const float* bn3b = (const float*)d_in[16];
    const float* bn3m = (const float*)d_in[17];
    const float* bn3v = (const float*)d_in[18];
    const float* prw  = (const float*)d_in[19];
    const float* prb  = (const float*)d_in[20];
    const float* qw   = (const float*)d_in[21];
    const float* pw1  = (const float*)d_in[22];
    const float* pb1  = (const float*)d_in[23];
    const float* pw2  = (const float*)d_in[24];
    const float* pb2  = (const float*)d_in[25];

    const int N = in_sizes[0] / (3 * 224 * 224);   // 128

    // workspace layout (floats)
    float* c1o = (float*)d_ws;                         // N*32*56*56 = 12,845,056
    float* c2o = c1o + (size_t)N * 32 * 56 * 56;       // N*64*28*28 =  6,422,528
    float* wt1 = c2o + (size_t)N * 64 * 28 * 28;       // 147*32
    float* sc1 = wt1 + 147 * 32;  float* sh1 = sc1 + 32;
    float* wt2 = sh1 + 32;                             // 288*64
    float* sc2 = wt2 + 288 * 64;  float* sh2 = sc2 + 64;
    float* wt3 = sh2 + 64;                             // 576*128
    float* sc3 = wt3 + 576 * 128; float* sh3 = sc3 + 128;
    // conv3 split-K partials alias the (dead after conv2) c1o region:
    float* p3a = c1o;                                  // N*128*14*14 = 3,211,264
    float* p3b = c1o + (size_t)N * 128 * 14 * 14;

    prep_kernel<32, 147><<<19, 256, 0, stream>>>(c1w, c1b, bn1g, bn1b, bn1m, bn1v, wt1, sc1, sh1);
    prep_kernel<64, 288><<<72, 256, 0, stream>>>(c2w, c2b, bn2g, bn2b, bn2m, bn2v, wt2, sc2, sh2);
    prep_kernel<128, 576><<<288, 256, 0, stream>>>(c3w, c3bi, bn3g, bn3b, bn3m, bn3v, wt3, sc3, sh3);

    // conv1: M=401408, BM=256 -> 1568 blocks, 8x4 tile
    conv_gemm_kernel<3, 7, 4, 3, 224, 224, 56, 56, 32, 256, 32, 8, 4, 147, true, 4>
        <<<dim3(401408 / 256, 1, 1), 256, 0, stream>>>(x, wt1, sc1, sh1, c1o, N);
    // conv2: M=100352, BM=128, BN=32 -> (784, 2) = 1568 blocks, 4x4 tile
    conv_gemm_kernel<32, 3, 2, 1, 56, 56, 28, 28, 64, 128, 32, 4, 4, 288, true, 4>
        <<<dim3(100352 / 128, 2, 1), 256, 0, stream>>>(c1o, wt2, sc2, sh2, c2o, N);
    // conv3: M=25088, BM=64, BN=64, split-K x2 -> (392, 2, 2) = 1568 blocks, 4x4 tile
    conv_gemm_kernel<64, 3, 2, 1, 28, 28, 14, 14, 128, 64, 64, 4, 4, 288, false, 4>
        <<<dim3(25088 / 64, 2, 2), 256, 0, stream>>>(c2o, wt3, sc3, sh3, p3a, N);

    head_kernel<<<N, 256, 0, stream>>>(p3a, p3b, sc3, sh3, prw, prb, qw,
                                       pw1, pb1, pw2, pb2, (float*)d_out);
}

// Round 6
// 404.315 us; speedup vs baseline: 10.7257x; 1.0541x over previous
//
#include <hip/hip_runtime.h>
#include <math.h>

#define DEV __device__ __forceinline__

typedef __attribute__((ext_vector_type(8))) __bf16 bf16x8;
typedef __attribute__((ext_vector_type(4))) __bf16 bf16x4;
typedef __attribute__((ext_vector_type(2))) __bf16 bf16x2;
typedef __attribute__((ext_vector_type(4))) float f32x4;

DEV __bf16 to_bf16(float v) { return (__bf16)v; }
DEV __bf16 to_bf16(__bf16 v) { return v; }

// ============ prep: w fp32 [OC][KT] -> bf16 [OC][KT]; fold BN ============
template<int OC, int KT>
__global__ void prep_kernel(const float* __restrict__ w,
                            const float* __restrict__ cb,
                            const float* __restrict__ bg, const float* __restrict__ bb,
                            const float* __restrict__ bm, const float* __restrict__ bv,
                            __bf16* __restrict__ wb, float* __restrict__ scale,
                            float* __restrict__ shift)
{
    int tid = blockIdx.x * blockDim.x + threadIdx.x;
    if (tid < OC) {
        float sc = bg[tid] * rsqrtf(bv[tid] + 1e-5f);
        scale[tid] = sc;
        shift[tid] = (cb[tid] - bm[tid]) * sc + bb[tid];
    }
    int stride = gridDim.x * blockDim.x;
    for (int e = tid; e < OC * KT; e += stride)
        wb[e] = (__bf16)w[e];
}

// ============ bf16 MFMA implicit-GEMM conv ============
// D[oc][s] = sum_k W[oc][k] * im2col[k][s].  A-operand = weights (rows=oc),
// B-operand = im2col (cols=spatial).  Block: 32 oc x 128 spatial, BK=32.
// 4 waves; wave w owns spatial cols [w*32, w*32+32), all 32 oc.
// blockIdx.y = oc block, blockIdx.z = K-split chunk (EPI=false -> raw fp32 partials).
template<typename INT, typename OUTT,
         int IC, int KS, int S, int P, int IH, int IW, int OH, int OW, int OC,
         int KCH, bool EPI>
__global__ __launch_bounds__(256, 4) void conv_mfma_kernel(
    const INT* __restrict__ x,        // (N,IC,IH,IW)
    const __bf16* __restrict__ wb,    // (OC,KT) bf16
    const float* __restrict__ scale,  // (OC)
    const float* __restrict__ shift,  // (OC)
    OUTT* __restrict__ out,           // (N,OC,OH,OW) [+ z offset]
    int batchN)
{
    constexpr int KT = IC * KS * KS;
    constexpr int KITER = (KCH + 31) / 32;
    constexpr int OHW = OH * OW;
    constexpr int LDR = 40;     // row pitch in halfs (32 + 8 pad: b128 frag reads 2-way = free)

    __shared__ __bf16 Is[128 * LDR];   // im2col tile [spatial][k]
    __shared__ __bf16 Ws[32 * LDR];    // weight tile [oc][k]

    const int tid = threadIdx.x;
    const int sb0 = blockIdx.x * 128;
    const int oc0 = blockIdx.y * 32;
    const int kz0 = blockIdx.z * KCH;
    OUTT* outp = out + (size_t)blockIdx.z * ((size_t)batchN * OC * OHW);

    // --- staging coords: this thread always stages spatial row sm, k-pairs kpb,kpb+2,... ---
    const int sm = tid & 127;
    const int kpb = tid >> 7;          // 0 or 1
    int a_n, a_ih0, a_iw0;
    {
        int m = sb0 + sm;
        a_n = m / OHW;
        int rem = m % OHW;
        a_ih0 = (rem / OW) * S - P;
        a_iw0 = (rem % OW) * S - P;
    }
    // weight staging coords: 4 consecutive k for one oc row
    const int w_oc = tid & 31;
    const int w_kq = tid >> 5;         // 0..7

    const int wave = tid >> 6, lane = tid & 63;
    const int quad = lane >> 4, l16 = lane & 15;

    f32x4 acc[2][2] = {};

    for (int kt = 0; kt < KITER; ++kt) {
        const int k0 = kz0 + kt * 32;

        // ---- gather im2col: 8 bf16-pairs into regs ----
        bf16x2 av[8];
        #pragma unroll
        for (int i = 0; i < 8; ++i) {
            int kp = 2 * i + kpb;      // 0..15
            __bf16 vv[2];
            #pragma unroll
            for (int j = 0; j < 2; ++j) {
                int kg = k0 + 2 * kp + j;
                int ic = kg / (KS * KS);
                int r2 = kg % (KS * KS);
                int kh = r2 / KS, kw = r2 % KS;
                int ih = a_ih0 + kh, iw = a_iw0 + kw;
                bool ok = (kg < KT) && ih >= 0 && ih < IH && iw >= 0 && iw < IW;
                vv[j] = ok ? to_bf16(x[((a_n * IC + ic) * IH + ih) * IW + iw])
                           : (__bf16)0.f;
            }
            av[i] = (bf16x2){vv[0], vv[1]};
        }
        // ---- gather weights: 4 halfs ----
        bf16x4 wv;
        #pragma unroll
        for (int j = 0; j < 4; ++j) {
            int kg = k0 + w_kq * 4 + j;
            wv[j] = (kg < KT) ? wb[(oc0 + w_oc) * KT + kg] : (__bf16)0.f;
        }

        __syncthreads();   // previous MFMA reads done before LDS overwrite
        #pragma unroll
        for (int i = 0; i < 8; ++i) {
            int kp = 2 * i + kpb;
            *(bf16x2*)&Is[sm * LDR + 2 * kp] = av[i];
        }
        *(bf16x4*)&Ws[w_oc * LDR + w_kq * 4] = wv;
        __syncthreads();

        // ---- 4 MFMA: 32oc x 32s per wave ----
        bf16x8 afr[2], bfr[2];
        #pragma unroll
        for (int mt = 0; mt < 2; ++mt)
            afr[mt] = *(const bf16x8*)&Ws[(mt * 16 + l16) * LDR + quad * 8];
        #pragma unroll
        for (int nt = 0; nt < 2; ++nt)
            bfr[nt] = *(const bf16x8*)&Is[(wave * 32 + nt * 16 + l16) * LDR + quad * 8];
        #pragma unroll
        for (int mt = 0; mt < 2; ++mt)
            #pragma unroll
            for (int nt = 0; nt < 2; ++nt)
                acc[mt][nt] = __builtin_amdgcn_mfma_f32_16x16x32_bf16(
                    afr[mt], bfr[nt], acc[mt][nt], 0, 0, 0);
    }

    // ---- epilogue: D row = oc (quad*4+r), col = spatial (l16) ----
    #pragma unroll
    for (int mt = 0; mt < 2; ++mt) {
        #pragma unroll
        for (int r = 0; r < 4; ++r) {
            int oc = oc0 + mt * 16 + quad * 4 + r;
            float scl = EPI ? scale[oc] : 0.f;
            float shf = EPI ? shift[oc] : 0.f;
            #pragma unroll
            for (int nt = 0; nt < 2; ++nt) {
                int sg = sb0 + wave * 32 + nt * 16 + l16;
                int n = sg / OHW, s = sg % OHW;
                float v = acc[mt][nt][r];
                if (EPI) {
                    v = fmaf(v, scl, shf);
                    v = v > 0.f ? v : 0.f;
                }
                outp[((size_t)n * OC + oc) * OHW + s] = (OUTT)v;
            }
        }
    }
}

// ============ quantum gate helpers ============
DEV void gate_ry(float* re, float* im, int q, float th) {
    float c = cosf(th * 0.5f), s = sinf(th * 0.5f);
    int mask = 8 >> q;
    for (int i = 0; i < 16; ++i) {
        if (i & mask) continue;
        int j = i | mask;
        float r0 = re[i], i0 = im[i], r1 = re[j], i1 = im[j];
        re[i] = c * r0 - s * r1;  im[i] = c * i0 - s * i1;
        re[j] = s * r0 + c * r1;  im[j] = s * i0 + c * i1;
    }
}
DEV void gate_rx(float* re, float* im, int q, float th) {
    float c = cosf(th * 0.5f), s = sinf(th * 0.5f);
    int mask = 8 >> q;
    for (int i = 0; i < 16; ++i) {
        if (i & mask) continue;
        int j = i | mask;
        float r0 = re[i], i0 = im[i], r1 = re[j], i1 = im[j];
        re[i] = c * r0 + s * i1;  im[i] = c * i0 - s * r1;
        re[j] = s * i0 + c * r1;  im[j] = -s * r0 + c * i1;
    }
}
DEV void gate_rz(float* re, float* im, int q, float th) {
    float c = cosf(th * 0.5f), s = sinf(th * 0.5f);
    int mask = 8 >> q;
    for (int i = 0; i < 16; ++i) {
        float sg = (i & mask) ? s : -s;
        float r = re[i], m = im[i];
        re[i] = c * r - sg * m;
        im[i] = c * m + sg * r;
    }
}
DEV void gate_cnot(float* re, float* im, int c, int t) {
    int cm = 8 >> c, tm = 8 >> t;
    for (int i = 0; i < 16; ++i) {
        if ((i & cm) && !(i & tm)) {
            int j = i | tm;
            float r = re[i]; re[i] = re[j]; re[j] = r;
            float m = im[i]; im[i] = im[j]; im[j] = m;
        }
    }
}

// ============ fused head: BN3+ReLU+pool -> linear/tanh -> circuit -> MLP ============
__global__ __launch_bounds__(256) void head_kernel(
    const float* __restrict__ p3a,       // (N,128,14,14) raw partial (K 0..287)
    const float* __restrict__ p3b,       // (N,128,14,14) raw partial (K 288..575)
    const float* __restrict__ sc3, const float* __restrict__ sh3,
    const float* __restrict__ pre_w, const float* __restrict__ pre_b,
    const float* __restrict__ qw,
    const float* __restrict__ pw1, const float* __restrict__ pb1,
    const float* __restrict__ pw2, const float* __restrict__ pb2,
    float* __restrict__ out)             // (N,5)
{
    __shared__ float f[512];
    __shared__ float ang[4];
    __shared__ float sre[16], simg[16];
    __shared__ float zexp[4];
    __shared__ float h1[64];

    int b = blockIdx.x;
    int t = threadIdx.x;

    size_t boff = (size_t)b * 128 * 196;
    for (int p = t; p < 512; p += 256) {
        int c = p >> 2, i = (p >> 1) & 1, j = p & 1;
        size_t base = boff + c * 196 + (i * 7) * 14 + j * 7;
        float scl = sc3[c], shf = sh3[c];
        float s = 0.f;
        #pragma unroll
        for (int u = 0; u < 7; ++u)
            #pragma unroll
            for (int v = 0; v < 7; ++v) {
                size_t idx = base + u * 14 + v;
                float val = fmaf(p3a[idx] + p3b[idx], scl, shf);
                s += val > 0.f ? val : 0.f;
            }
        f[p] = s * (1.f / 49.f);
    }
    __syncthreads();

    int wv = t >> 6, lane = t & 63;
    float partial = 0.f;
    for (int d = lane; d < 512; d += 64)
        partial += f[d] * pre_w[wv * 512 + d];
    #pragma unroll
    for (int off = 32; off > 0; off >>= 1)
        partial += __shfl_down(partial, off, 64);
    if (lane == 0)
        ang[wv] = tanhf(partial + pre_b[wv]) * 3.14159265358979323846f;
    __syncthreads();

    if (t == 0) {
        for (int i = 0; i < 16; ++i) { sre[i] = 0.f; simg[i] = 0.f; }
        sre[0] = 1.f;
        for (int q = 0; q < 4; ++q) gate_ry(sre, simg, q, ang[q]);
        for (int l = 0; l < 2; ++l) {
            for (int q = 0; q < 4; ++q) {
                const float* qq = qw + (l * 4 + q) * 3;
                gate_rx(sre, simg, q, qq[0]);
                gate_ry(sre, simg, q, qq[1]);
                gate_rz(sre, simg, q, qq[2]);
            }
            gate_cnot(sre, simg, 0, 1);
            gate_cnot(sre, simg, 1, 2);
            gate_cnot(sre, simg, 2, 3);
            gate_cnot(sre, simg, 3, 0);
        }
        for (int q = 0; q < 4; ++q) {
            float z = 0.f;
            for (int i = 0; i < 16; ++i) {
                float p2 = sre[i] * sre[i] + simg[i] * simg[i];
                z += (((i >> (3 - q)) & 1) ? -p2 : p2);
            }
            zexp[q] = z;
        }
    }
    __syncthreads();

    if (t < 64) {
        float s = pb1[t];
        #pragma unroll
        for (int k = 0; k < 4; ++k) s += zexp[k] * pw1[t * 4 + k];
        h1[t] = s > 0.f ? s : 0.f;
    }
    __syncthreads();

    if (t < 5) {
        float s = pb2[t];
        for (int k = 0; k < 64; ++k) s += h1[k] * pw2[t * 64 + k];
        out[b * 5 + t] = s;
    }
}

extern "C" void kernel_launch(void* const* d_in, const int* in_sizes, int n_in,
                              void* d_out, int out_size, void* d_ws, size_t ws_size,
                              hipStream_t stream) {
    const float* x    = (const float*)d_in[0];
    const float* c1w  = (const float*)d_in[1];
    const float* c1b  = (const float*)d_in[2];
    const float* bn1g = (const float*)d_in[3];
    const float* bn1b = (const float*)d_in[4];
    const float* bn1m = (const float*)d_in[5];
    const float* bn1v = (const float*)d_in[6];
    const float* c2w  = (const float*)d_in[7];
    const float* c2b  = (const float*)d_in[8];
    const float* bn2g = (const float*)d_in[9];
    const float* bn2b = (const float*)d_in[10];
    const float* bn2m = (const float*)d_in[11];
    const float* bn2v = (const float*)d_in[12];
    const float* c3w  = (const float*)d_in[13];
    const float* c3bi = (const float*)d_in[14];
    const float* bn3g = (const float*)d_in[15];
    const float* bn3b = (const float*)d_in[16];
    const float* bn3m = (const float*)d_in[17];
    const float* bn3v = (const float*)d_in[18];
    const float* prw  = (const float*)d_in[19];
    const float* prb  = (const float*)d_in[20];
    const float* qw   = (const float*)d_in[21];
    const float* pw1  = (const float*)d_in[22];
    const float* pb1  = (const float*)d_in[23];
    const float* pw2  = (const float*)d_in[24];
    const float* pb2  = (const float*)d_in[25];

    const int N = in_sizes[0] / (3 * 224 * 224);   // 128

    // ---- workspace layout ----
    // bf16 section
    __bf16* c1o = (__bf16*)d_ws;                     // N*32*56*56 = 12,845,056 halfs
    __bf16* c2o = c1o + (size_t)N * 32 * 56 * 56;    // N*64*28*28 =  6,422,528 halfs
    __bf16* wb1 = c2o + (size_t)N * 64 * 28 * 28;    // 32*147  = 4704
    __bf16* wb2 = wb1 + 32 * 147;                    // 64*288  = 18432
    __bf16* wb3 = wb2 + 64 * 288;                    // 128*576 = 73728
    // float section (offset is 4-byte aligned: total halfs so far is even)
    float* sc1 = (float*)(wb3 + 128 * 576);
    float* sh1 = sc1 + 32;
    float* sc2 = sh1 + 32;  float* sh2 = sc2 + 64;
    float* sc3 = sh2 + 64;  float* sh3 = sc3 + 128;
    // conv3 split-K fp32 partials alias the (dead after conv2) c1o region:
    // 2 * N*128*14*14 floats = 25,690,112 B == c1o's 12,845,056 halfs exactly.
    float* p3a = (float*)d_ws;
    float* p3b = p3a + (size_t)N * 128 * 14 * 14;

    prep_kernel<32, 147><<<19, 256, 0, stream>>>(c1w, c1b, bn1g, bn1b, bn1m, bn1v, wb1, sc1, sh1);
    prep_kernel<64, 288><<<72, 256, 0, stream>>>(c2w, c2b, bn2g, bn2b, bn2m, bn2v, wb2, sc2, sh2);
    prep_kernel<128, 576><<<288, 256, 0, stream>>>(c3w, c3bi, bn3g, bn3b, bn3m, bn3v, wb3, sc3, sh3);

    // conv1: fp32 in -> bf16 out.  M=401408 spatial -> 3136 blocks.
    conv_mfma_kernel<float, __bf16, 3, 7, 4, 3, 224, 224, 56, 56, 32, 147, true>
        <<<dim3(401408 / 128, 1, 1), 256, 0, stream>>>(x, wb1, sc1, sh1, c1o, N);
    // conv2: bf16 in -> bf16 out.  M=100352 -> (784, 2) blocks.
    conv_mfma_kernel<__bf16, __bf16, 32, 3, 2, 1, 56, 56, 28, 28, 64, 288, true>
        <<<dim3(100352 / 128, 2, 1), 256, 0, stream>>>(c1o, wb2, sc2, sh2, c2o, N);
    // conv3: bf16 in -> fp32 raw partials, split-K x2.  (196, 4, 2) blocks.
    conv_mfma_kernel<__bf16, float, 64, 3, 2, 1, 28, 28, 14, 14, 128, 288, false>
        <<<dim3(25088 / 128, 4, 2), 256, 0, stream>>>(c2o, wb3, sc3, sh3, p3a, N);

    head_kernel<<<N, 256, 0, stream>>>(p3a, p3b, sc3, sh3, prw, prb, qw,
                                       pw1, pb1, pw2, pb2, (float*)d_out);
}

// Round 7
// 351.862 us; speedup vs baseline: 12.3247x; 1.1491x over previous
//
#include <hip/hip_runtime.h>
#include <math.h>

#define DEV __device__ __forceinline__

typedef __attribute__((ext_vector_type(8))) __bf16 bf16x8;
typedef __attribute__((ext_vector_type(4))) float f32x4;

DEV __bf16 to_bf16(float v) { return (__bf16)v; }
DEV __bf16 to_bf16(__bf16 v) { return v; }

// ============ prep (single dispatch): all weights fp32->bf16 (K-padded); fold BN ============
__global__ void prep_all(
    const float* __restrict__ c1w, const float* __restrict__ c1b,
    const float* __restrict__ g1, const float* __restrict__ b1,
    const float* __restrict__ m1, const float* __restrict__ v1,
    const float* __restrict__ c2w, const float* __restrict__ c2b,
    const float* __restrict__ g2, const float* __restrict__ b2,
    const float* __restrict__ m2, const float* __restrict__ v2,
    const float* __restrict__ c3w, const float* __restrict__ c3b,
    const float* __restrict__ g3, const float* __restrict__ b3,
    const float* __restrict__ m3, const float* __restrict__ v3,
    __bf16* __restrict__ wb1, __bf16* __restrict__ wb2, __bf16* __restrict__ wb3,
    float* __restrict__ sc1, float* __restrict__ sh1,
    float* __restrict__ sc2, float* __restrict__ sh2,
    float* __restrict__ sc3, float* __restrict__ sh3)
{
    int gid = blockIdx.x * 256 + threadIdx.x;
    int gs = gridDim.x * 256;
    for (int e = gid; e < 32 * 160; e += gs) {
        int oc = e / 160, k = e % 160;
        wb1[e] = (k < 147) ? (__bf16)c1w[oc * 147 + k] : (__bf16)0.f;
    }
    for (int e = gid; e < 64 * 288; e += gs) wb2[e] = (__bf16)c2w[e];
    for (int e = gid; e < 128 * 576; e += gs) wb3[e] = (__bf16)c3w[e];
    if (gid < 32) {
        float s = g1[gid] * rsqrtf(v1[gid] + 1e-5f);
        sc1[gid] = s; sh1[gid] = (c1b[gid] - m1[gid]) * s + b1[gid];
    } else if (gid < 96) {
        int i = gid - 32;
        float s = g2[i] * rsqrtf(v2[i] + 1e-5f);
        sc2[i] = s; sh2[i] = (c2b[i] - m2[i]) * s + b2[i];
    } else if (gid < 224) {
        int i = gid - 96;
        float s = g3[i] * rsqrtf(v3[i] + 1e-5f);
        sc3[i] = s; sh3[i] = (c3b[i] - m3[i]) * s + b3[i];
    }
}

// ============ bf16 MFMA implicit-GEMM conv ============
// D[oc][s] = sum_k W[oc][k] * im2col[k][s]. Block: 32 oc x 128 spatial, BK=32.
// KOFF is a template constant (split-K = separate launches) so the fully
// unrolled K loop makes every kg compile-time: ic/kh/kw constant-fold.
// Staging: thread -> (row sm, 16 consecutive k) => two ds_write_b128
// (80B row stride x b128 = all 32 banks hit exactly 8 dwords: conflict-free).
template<typename INT, typename OUTT,
         int IC, int KS, int S, int P, int IH, int IW, int OH, int OW, int OC,
         int KTP, int KOFF, int KCH, bool EPI>
__global__ __launch_bounds__(256, 4) void conv_mfma_kernel(
    const INT* __restrict__ x,        // (N,IC,IH,IW)
    const __bf16* __restrict__ wb,    // (OC,KTP) bf16, zero-padded
    const float* __restrict__ scale,  // (OC)
    const float* __restrict__ shift,  // (OC)
    OUTT* __restrict__ out)           // (N,OC,OH,OW)
{
    constexpr int KT = IC * KS * KS;
    constexpr int KITER = (KCH + 31) / 32;
    constexpr int OHW = OH * OW;
    constexpr int IHW = IH * IW;
    constexpr int LDR = 40;   // halfs per row (32 data + 8 pad); rows 16B-aligned

    __shared__ __attribute__((aligned(16))) __bf16 Is[128 * LDR]; // [spatial][k]
    __shared__ __attribute__((aligned(16))) __bf16 Ws[32 * LDR];  // [oc][k]

    const int tid = threadIdx.x;
    const int sb0 = blockIdx.x * 128;
    const int oc0 = blockIdx.y * 32;

    // --- Is staging coords: row sm, k in [kpb*16, kpb*16+16) (kpb wave-uniform) ---
    const int sm = tid & 127;
    const int kpb = tid >> 7;
    int a_n, a_ih0, a_iw0;
    {
        int m = sb0 + sm;
        a_n = m / OHW;
        int rem = m % OHW;
        a_ih0 = (rem / OW) * S - P;
        a_iw0 = (rem % OW) * S - P;
    }
    unsigned ihok = 0, iwok = 0;
    #pragma unroll
    for (int t = 0; t < KS; ++t) {
        ihok |= (unsigned)(((a_ih0 + t) >= 0) && ((a_ih0 + t) < IH)) << t;
        iwok |= (unsigned)(((a_iw0 + t) >= 0) && ((a_iw0 + t) < IW)) << t;
    }
    const INT* xp = x + (size_t)a_n * IC * IHW + (ptrdiff_t)a_ih0 * IW + a_iw0;

    auto gather = [&](int kg) -> __bf16 {
        if (kg >= KT) return (__bf16)0.f;          // compile-time after unroll
        const int ic = kg / (KS * KS);
        const int r  = kg % (KS * KS);
        const int kh = r / KS, kw = r % KS;
        bool ok = ((ihok >> kh) & 1u) && ((iwok >> kw) & 1u);
        __bf16 v = (__bf16)0.f;
        if (ok) v = to_bf16(xp[ic * IHW + kh * IW + kw]);
        return v;
    };

    // --- Ws staging coords (threads 0..127): oc row, 8-k octet j ---
    const int w_oc = tid >> 2;      // 0..31 for tid<128
    const int w_j  = tid & 3;

    const int wave = tid >> 6, lane = tid & 63;
    const int quad = lane >> 4, l16 = lane & 15;

    f32x4 acc[2][2] = {};

    #pragma unroll
    for (int ci = 0; ci < KITER; ++ci) {
        const int k0 = KOFF + ci * 32;

        bf16x8 v0, v1;
        if (kpb == 0) {
            #pragma unroll
            for (int j = 0; j < 8; ++j) v0[j] = gather(k0 + j);
            #pragma unroll
            for (int j = 0; j < 8; ++j) v1[j] = gather(k0 + 8 + j);
        } else {
            #pragma unroll
            for (int j = 0; j < 8; ++j) v0[j] = gather(k0 + 16 + j);
            #pragma unroll
            for (int j = 0; j < 8; ++j) v1[j] = gather(k0 + 24 + j);
        }
        bf16x8 wv = {};
        if (tid < 128)
            wv = *(const bf16x8*)&wb[(size_t)(oc0 + w_oc) * KTP + k0 + w_j * 8];

        __syncthreads();   // prev chunk's frag reads done before overwrite
        *(bf16x8*)&Is[sm * LDR + kpb * 16]     = v0;
        *(bf16x8*)&Is[sm * LDR + kpb * 16 + 8] = v1;
        if (tid < 128) *(bf16x8*)&Ws[w_oc * LDR + w_j * 8] = wv;
        __syncthreads();

        bf16x8 afr[2], bfr[2];
        #pragma unroll
        for (int mt = 0; mt < 2; ++mt)
            afr[mt] = *(const bf16x8*)&Ws[(mt * 16 + l16) * LDR + quad * 8];
        #pragma unroll
        for (int nt = 0; nt < 2; ++nt)
            bfr[nt] = *(const bf16x8*)&Is[(wave * 32 + nt * 16 + l16) * LDR + quad * 8];
        #pragma unroll
        for (int mt = 0; mt < 2; ++mt)
            #pragma unroll
            for (int nt = 0; nt < 2; ++nt)
                acc[mt][nt] = __builtin_amdgcn_mfma_f32_16x16x32_bf16(
                    afr[mt], bfr[nt], acc[mt][nt], 0, 0, 0);
    }

    // ---- epilogue: D row = oc (quad*4+r), col = spatial (l16) ----
    #pragma unroll
    for (int mt = 0; mt < 2; ++mt) {
        #pragma unroll
        for (int r = 0; r < 4; ++r) {
            int oc = oc0 + mt * 16 + quad * 4 + r;
            float scl = EPI ? scale[oc] : 0.f;
            float shf = EPI ? shift[oc] : 0.f;
            #pragma unroll
            for (int nt = 0; nt < 2; ++nt) {
                int sg = sb0 + wave * 32 + nt * 16 + l16;
                int n = sg / OHW, s = sg % OHW;
                float v = acc[mt][nt][r];
                if (EPI) {
                    v = fmaf(v, scl, shf);
                    v = v > 0.f ? v : 0.f;
                }
                out[((size_t)n * OC + oc) * OHW + s] = (OUTT)v;
            }
        }
    }
}

// ============ quantum gate helpers ============
DEV void gate_ry(float* re, float* im, int q, float th) {
    float c = cosf(th * 0.5f), s = sinf(th * 0.5f);
    int mask = 8 >> q;
    for (int i = 0; i < 16; ++i) {
        if (i & mask) continue;
        int j = i | mask;
        float r0 = re[i], i0 = im[i], r1 = re[j], i1 = im[j];
        re[i] = c * r0 - s * r1;  im[i] = c * i0 - s * i1;
        re[j] = s * r0 + c * r1;  im[j] = s * i0 + c * i1;
    }
}
DEV void gate_rx(float* re, float* im, int q, float th) {
    float c = cosf(th * 0.5f), s = sinf(th * 0.5f);
    int mask = 8 >> q;
    for (int i = 0; i < 16; ++i) {
        if (i & mask) continue;
        int j = i | mask;
        float r0 = re[i], i0 = im[i], r1 = re[j], i1 = im[j];
        re[i] = c * r0 + s * i1;  im[i] = c * i0 - s * r1;
        re[j] = s * i0 + c * r1;  im[j] = -s * r0 + c * i1;
    }
}
DEV void gate_rz(float* re, float* im, int q, float th) {
    float c = cosf(th * 0.5f), s = sinf(th * 0.5f);
    int mask = 8 >> q;
    for (int i = 0; i < 16; ++i) {
        float sg = (i & mask) ? s : -s;
        float r = re[i], m = im[i];
        re[i] = c * r - sg * m;
        im[i] = c * m + sg * r;
    }
}
DEV void gate_cnot(float* re, float* im, int c, int t) {
    int cm = 8 >> c, tm = 8 >> t;
    for (int i = 0; i < 16; ++i) {
        if ((i & cm) && !(i & tm)) {
            int j = i | tm;
            float r = re[i]; re[i] = re[j]; re[j] = r;
            float m = im[i]; im[i] = im[j]; im[j] = m;
        }
    }
}

// ============ fused head: BN3+ReLU+pool -> linear/tanh -> circuit -> MLP ============
__global__ __launch_bounds__(256) void head_kernel(
    const float* __restrict__ p3a,       // (N,128,14,14) raw partial (K 0..287)
    const float* __restrict__ p3b,       // (N,128,14,14) raw partial (K 288..575)
    const float* __restrict__ sc3, const float* __restrict__ sh3,
    const float* __restrict__ pre_w, const float* __restrict__ pre_b,
    const float* __restrict__ qw,
    const float* __restrict__ pw1, const float* __restrict__ pb1,
    const float* __restrict__ pw2, const float* __restrict__ pb2,
    float* __restrict__ out)             // (N,5)
{
    __shared__ float f[512];
    __shared__ float ang[4];
    __shared__ float sre[16], simg[16];
    __shared__ float zexp[4];
    __shared__ float h1[64];

    int b = blockIdx.x;
    int t = threadIdx.x;

    size_t boff = (size_t)b * 128 * 196;
    for (int p = t; p < 512; p += 256) {
        int c = p >> 2, i = (p >> 1) & 1, j = p & 1;
        size_t base = boff + c * 196 + (i * 7) * 14 + j * 7;
        float scl = sc3[c], shf = sh3[c];
        float s = 0.f;
        #pragma unroll
        for (int u = 0; u < 7; ++u)
            #pragma unroll
            for (int v = 0; v < 7; ++v) {
                size_t idx = base + u * 14 + v;
                float val = fmaf(p3a[idx] + p3b[idx], scl, shf);
                s += val > 0.f ? val : 0.f;
            }
        f[p] = s * (1.f / 49.f);
    }
    __syncthreads();

    int wv = t >> 6, lane = t & 63;
    float partial = 0.f;
    for (int d = lane; d < 512; d += 64)
        partial += f[d] * pre_w[wv * 512 + d];
    #pragma unroll
    for (int off = 32; off > 0; off >>= 1)
        partial += __shfl_down(partial, off, 64);
    if (lane == 0)
        ang[wv] = tanhf(partial + pre_b[wv]) * 3.14159265358979323846f;
    __syncthreads();

    if (t == 0) {
        for (int i = 0; i < 16; ++i) { sre[i] = 0.f; simg[i] = 0.f; }
        sre[0] = 1.f;
        for (int q = 0; q < 4; ++q) gate_ry(sre, simg, q, ang[q]);
        for (int l = 0; l < 2; ++l) {
            for (int q = 0; q < 4; ++q) {
                const float* qq = qw + (l * 4 + q) * 3;
                gate_rx(sre, simg, q, qq[0]);
                gate_ry(sre, simg, q, qq[1]);
                gate_rz(sre, simg, q, qq[2]);
            }
            gate_cnot(sre, simg, 0, 1);
            gate_cnot(sre, simg, 1, 2);
            gate_cnot(sre, simg, 2, 3);
            gate_cnot(sre, simg, 3, 0);
        }
        for (int q = 0; q < 4; ++q) {
            float z = 0.f;
            for (int i = 0; i < 16; ++i) {
                float p2 = sre[i] * sre[i] + simg[i] * simg[i];
                z += (((i >> (3 - q)) & 1) ? -p2 : p2);
            }
            zexp[q] = z;
        }
    }
    __syncthreads();

    if (t < 64) {
        float s = pb1[t];
        #pragma unroll
        for (int k = 0; k < 4; ++k) s += zexp[k] * pw1[t * 4 + k];
        h1[t] = s > 0.f ? s : 0.f;
    }
    __syncthreads();

    if (t < 5) {
        float s = pb2[t];
        for (int k = 0; k < 64; ++k) s += h1[k] * pw2[t * 64 + k];
        out[b * 5 + t] = s;
    }
}

extern "C" void kernel_launch(void* const* d_in, const int* in_sizes, int n_in,
                              void* d_out, int out_size, void* d_ws, size_t ws_size,
                              hipStream_t stream) {
    const float* x    = (const float*)d_in[0];
    const float* c1w  = (const float*)d_in[1];
    const float* c1b  = (const float*)d_in[2];
    const float* bn1g = (const float*)d_in[3];
    const float* bn1b = (const float*)d_in[4];
    const float* bn1m = (const float*)d_in[5];
    const float* bn1v = (const float*)d_in[6];
    const float* c2w  = (const float*)d_in[7];
    const float* c2b  = (const float*)d_in[8];
    const float* bn2g = (const float*)d_in[9];
    const float* bn2b = (const float*)d_in[10];
    const float* bn2m = (const float*)d_in[11];
    const float* bn2v = (const float*)d_in[12];
    const float* c3w  = (const float*)d_in[13];
    const float* c3bi = (const float*)d_in[14];
    const float* bn3g = (const float*)d_in[15];
    const float* bn3b = (const float*)d_in[16];
    const float* bn3m = (const float*)d_in[17];
    const float* bn3v = (const float*)d_in[18];
    const float* prw  = (const float*)d_in[19];
    const float* prb  = (const float*)d_in[20];
    const float* qw   = (const float*)d_in[21];
    const float* pw1  = (const float*)d_in[22];
    const float* pb1  = (const float*)d_in[23];
    const float* pw2  = (const float*)d_in[24];
    const float* pb2  = (const float*)d_in[25];

    const int N = in_sizes[0] / (3 * 224 * 224);   // 128

    // ---- workspace layout ----
    __bf16* c1o = (__bf16*)d_ws;                     // N*32*56*56 = 12,845,056 halfs
    __bf16* c2o = c1o + (size_t)N * 32 * 56 * 56;    // N*64*28*28 =  6,422,528 halfs
    __bf16* wb1 = c2o + (size_t)N * 64 * 28 * 28;    // 32*160  = 5120 (16B-aligned)
    __bf16* wb2 = wb1 + 32 * 160;                    // 64*288  = 18432
    __bf16* wb3 = wb2 + 64 * 288;                    // 128*576 = 73728
    float* sc1 = (float*)(wb3 + 128 * 576);
    float* sh1 = sc1 + 32;
    float* sc2 = sh1 + 32;  float* sh2 = sc2 + 64;
    float* sc3 = sh2 + 64;  float* sh3 = sc3 + 128;
    // conv3 split-K fp32 partials alias the (dead after conv2) c1o region:
    // 2 * N*128*14*14 floats = 25,690,112 B == c1o's 12,845,056 halfs exactly.
    float* p3a = (float*)d_ws;
    float* p3b = p3a + (size_t)N * 128 * 14 * 14;

    prep_all<<<380, 256, 0, stream>>>(
        c1w, c1b, bn1g, bn1b, bn1m, bn1v,
        c2w, c2b, bn2g, bn2b, bn2m, bn2v,
        c3w, c3bi, bn3g, bn3b, bn3m, bn3v,
        wb1, wb2, wb3, sc1, sh1, sc2, sh2, sc3, sh3);

    // conv1: fp32 in -> bf16 out.  KTP=160, KOFF=0, KCH=160 (KT=147 zero-padded).
    conv_mfma_kernel<float, __bf16, 3, 7, 4, 3, 224, 224, 56, 56, 32, 160, 0, 160, true>
        <<<dim3(401408 / 128, 1), 256, 0, stream>>>(x, wb1, sc1, sh1, c1o);
    // conv2: bf16 in -> bf16 out.  KTP=288, full K.
    conv_mfma_kernel<__bf16, __bf16, 32, 3, 2, 1, 56, 56, 28, 28, 64, 288, 0, 288, true>
        <<<dim3(100352 / 128, 2), 256, 0, stream>>>(c1o, wb2, sc2, sh2, c2o);
    // conv3: bf16 in -> fp32 raw partials, split-K as two constexpr-offset launches.
    conv_mfma_kernel<__bf16, float, 64, 3, 2, 1, 28, 28, 14, 14, 128, 576, 0, 288, false>
        <<<dim3(25088 / 128, 4), 256, 0, stream>>>(c2o, wb3, sc3, sh3, p3a);
    conv_mfma_kernel<__bf16, float, 64, 3, 2, 1, 28, 28, 14, 14, 128, 576, 288, 288, false>
        <<<dim3(25088 / 128, 4), 256, 0, stream>>>(c2o, wb3, sc3, sh3, p3b);

    head_kernel<<<N, 256, 0, stream>>>(p3a, p3b, sc3, sh3, prw, prb, qw,
                                       pw1, pb1, pw2, pb2, (float*)d_out);
}